// Round 11
// baseline (1130.777 us; speedup 1.0000x reference)
//
#include <hip/hip_runtime.h>
#include <stdint.h>

typedef unsigned long long u64;
typedef unsigned int u32;
typedef unsigned char u8;

// ---------------------------------------------------------------------------
// EdgePool GNN pipeline.  N=100000, E=800000, F=128, H=64, G=8, C=10. f32.
// R1 two-stage gmp · R2 dst-CSR gather · R4 match state in LDS · R5 XCD
// swizzle + epoch bcur + no-max softmax · R7 wave-per-node gfin2 + partial
// gmp flush + two-phase build · R8 CSR-ordered scoring · R9 grid-wide
// matching round 0 · R14 LDS-resident match mid-tail · R16 prefetch +
// score-in-key + per-graph head · R18 gfin2 unroll + fused scan · R19
// O(N) match0 · R20 2-node o-quarter transform + gfin2 x8 + u8 dead.
// R21: dispatch-count reduction (~24 launches; est. ~7us gap each).
//      (a) scan_sums+scan_out pair -> ONE decoupled-lookback scan kernel
//      (98 blocks << 256 CUs -> all co-resident -> spin-safe; flags live
//      in the zeroed block, separate set per call site). Saves 2 launches
//      + a full cnt re-read per scan. (b) bcur0 ~0-init folded into the
//      first k_fill (E >= N threads), saving the second memset launch.
//      match_wg untouched (R14-R19 established it as a local optimum).
// ---------------------------------------------------------------------------

// 1D grid = chunks*4, chunks % 8 == 0.  bid -> {xcd=bid&7, oq=(bid>>3)&3,
// chunk=(bid>>5)*8+xcd}: a chunk's 4 o-quarter blocks share an XCD.
template <int K>
__global__ __launch_bounds__(256) void k_transform2(
    const float* __restrict__ x, const float* __restrict__ wrel,
    const float* __restrict__ wroot, const float* __restrict__ bias,
    const int* __restrict__ nvP, float* __restrict__ r,
    float* __restrict__ u, int n) {
  __shared__ float wsR[16 * K];
  __shared__ float wsU[16 * K];
  int xcd = blockIdx.x & 7;
  int s = blockIdx.x >> 3;
  int oq = s & 3;
  int chunk = (s >> 2) * 8 + xcd;
  const int ob = oq * 16;
  const float* __restrict__ wA = wrel + (size_t)ob * K;
  const float* __restrict__ wB = wroot + (size_t)ob * K;
  for (int i = threadIdx.x; i < 4 * K; i += 256) {
    reinterpret_cast<float4*>(wsR)[i] = reinterpret_cast<const float4*>(wA)[i];
    reinterpret_cast<float4*>(wsU)[i] = reinterpret_cast<const float4*>(wB)[i];
  }
  int nv = n;
  if (nvP) { int v = *nvP; if (v < nv) nv = v; }
  int node0 = chunk * 512 + threadIdx.x;
  int node1 = node0 + 256;
  bool act0 = node0 < nv;
  bool act1 = node1 < nv;
  __syncthreads();
  if (!(act0 | act1)) return;
  // clamp inactive rows to row 0: harmless reads, writes guarded below
  const float* xr0 = x + (size_t)(act0 ? node0 : 0) * K;
  const float* xr1 = x + (size_t)(act1 ? node1 : 0) * K;
  float aR0[16], aU0[16], aR1[16], aU1[16];
#pragma unroll
  for (int o = 0; o < 16; ++o) {
    float b = bias[ob + o];
    aR0[o] = 0.f; aR1[o] = 0.f;
    aU0[o] = b;   aU1[o] = b;
  }
  for (int k = 0; k < K; k += 4) {
    float4 xv0 = *reinterpret_cast<const float4*>(xr0 + k);
    float4 xv1 = *reinterpret_cast<const float4*>(xr1 + k);
#pragma unroll
    for (int o = 0; o < 16; ++o) {
      float4 wv = *reinterpret_cast<const float4*>(&wsR[o * K + k]);
      aR0[o] = fmaf(xv0.x, wv.x, aR0[o]);
      aR0[o] = fmaf(xv0.y, wv.y, aR0[o]);
      aR0[o] = fmaf(xv0.z, wv.z, aR0[o]);
      aR0[o] = fmaf(xv0.w, wv.w, aR0[o]);
      aR1[o] = fmaf(xv1.x, wv.x, aR1[o]);
      aR1[o] = fmaf(xv1.y, wv.y, aR1[o]);
      aR1[o] = fmaf(xv1.z, wv.z, aR1[o]);
      aR1[o] = fmaf(xv1.w, wv.w, aR1[o]);
      float4 wu = *reinterpret_cast<const float4*>(&wsU[o * K + k]);
      aU0[o] = fmaf(xv0.x, wu.x, aU0[o]);
      aU0[o] = fmaf(xv0.y, wu.y, aU0[o]);
      aU0[o] = fmaf(xv0.z, wu.z, aU0[o]);
      aU0[o] = fmaf(xv0.w, wu.w, aU0[o]);
      aU1[o] = fmaf(xv1.x, wu.x, aU1[o]);
      aU1[o] = fmaf(xv1.y, wu.y, aU1[o]);
      aU1[o] = fmaf(xv1.z, wu.z, aU1[o]);
      aU1[o] = fmaf(xv1.w, wu.w, aU1[o]);
    }
  }
  if (act0) {
    float4* op = reinterpret_cast<float4*>(r + (size_t)node0 * 64 + ob);
#pragma unroll
    for (int o = 0; o < 4; ++o)
      op[o] = make_float4(aR0[4 * o], aR0[4 * o + 1], aR0[4 * o + 2], aR0[4 * o + 3]);
    op = reinterpret_cast<float4*>(u + (size_t)node0 * 64 + ob);
#pragma unroll
    for (int o = 0; o < 4; ++o)
      op[o] = make_float4(aU0[4 * o], aU0[4 * o + 1], aU0[4 * o + 2], aU0[4 * o + 3]);
  }
  if (act1) {
    float4* op = reinterpret_cast<float4*>(r + (size_t)node1 * 64 + ob);
#pragma unroll
    for (int o = 0; o < 4; ++o)
      op[o] = make_float4(aR1[4 * o], aR1[4 * o + 1], aR1[4 * o + 2], aR1[4 * o + 3]);
    op = reinterpret_cast<float4*>(u + (size_t)node1 * 64 + ob);
#pragma unroll
    for (int o = 0; o < 4; ++o)
      op[o] = make_float4(aU1[4 * o], aU1[4 * o + 1], aU1[4 * o + 2], aU1[4 * o + 3]);
  }
}

// dst-degree count; 1024-edge chunks
__global__ void k_count(const int* __restrict__ dst, int* __restrict__ cnt, int e) {
  int base = blockIdx.x << 10;
#pragma unroll
  for (int k = 0; k < 4; ++k) {
    int i = base + k * 256 + threadIdx.x;
    if (i < e) atomicAdd(&cnt[dst[i]], 1);
  }
}

// R21: single-kernel exclusive scan via decoupled lookback.
// flags: [0..127]=state (0 none, 1 agg ready, 2 prefix ready),
//        [128..255]=aggregate, [256..383]=inclusive prefix.
// All blocks co-resident (nb <= 98 < 256 CUs) -> spin-wait is safe.
__global__ void k_scan(const int* __restrict__ in, int* __restrict__ rowptr,
                       int* __restrict__ pos, int* __restrict__ flags, int n) {
  __shared__ int sd[256];
  __shared__ int sbase;
  int* st = flags;
  int* aggv = flags + 128;
  int* prefv = flags + 256;
  int b = blockIdx.x;
  int base = b << 10;
  int i0 = base + threadIdx.x * 4;
  int v0 = 0, v1 = 0, v2 = 0, v3 = 0;
  if (i0 < n) v0 = in[i0];
  if (i0 + 1 < n) v1 = in[i0 + 1];
  if (i0 + 2 < n) v2 = in[i0 + 2];
  if (i0 + 3 < n) v3 = in[i0 + 3];
  sd[threadIdx.x] = v0 + v1 + v2 + v3;
  __syncthreads();
  for (int off = 1; off < 256; off <<= 1) {
    int add = (threadIdx.x >= off) ? sd[threadIdx.x - off] : 0;
    __syncthreads();
    sd[threadIdx.x] += add;
    __syncthreads();
  }
  if (threadIdx.x == 255) {
    int tot = sd[255];
    aggv[b] = tot;
    __threadfence();
    atomicExch(&st[b], 1);
    int excl = 0;
    int p = b - 1;
    while (p >= 0) {
      int s;
      do { s = atomicAdd(&st[p], 0); } while (s == 0);
      __threadfence();
      if (s == 2) { excl += prefv[p]; break; }
      excl += aggv[p];
      --p;
    }
    prefv[b] = excl + tot;
    __threadfence();
    atomicExch(&st[b], 2);
    sbase = excl;
  }
  __syncthreads();
  int excl = sbase + (threadIdx.x ? sd[threadIdx.x - 1] : 0);
  if (i0 < n) { rowptr[i0] = excl; pos[i0] = excl; }
  excl += v0;
  if (i0 + 1 < n) { rowptr[i0 + 1] = excl; pos[i0 + 1] = excl; }
  excl += v1;
  if (i0 + 2 < n) { rowptr[i0 + 2] = excl; pos[i0 + 2] = excl; }
  excl += v2;
  if (i0 + 3 < n) { rowptr[i0 + 3] = excl; pos[i0 + 3] = excl; }
}

// CSR fill: col = src, eid = original edge index.
// R21: optionally ~0-inits bcur0 (folds a memset launch; i<nb0 threads).
__global__ void k_fill(const int* __restrict__ src, const int* __restrict__ dst,
                       int* __restrict__ pos, int* __restrict__ col,
                       int* __restrict__ eid, u64* __restrict__ bc0, int nb0,
                       int e, int n) {
  int i = blockIdx.x * blockDim.x + threadIdx.x;
  if (i >= e) return;
  if (bc0 && i < nb0) bc0[i] = ~0ull;
  int d = dst[i];
  if (d >= n) return;  // sentinel (pooled duplicates)
  int j = atomicAdd(&pos[d], 1);
  col[j] = src[i];
  if (eid) eid[j] = i;
}

// R7 fused conv tail: wave-per-node gather + mean + relu + h-write (+dots),
// gmp accumulated in LDS, flushed to 64 partial buffers (presence-masked).
// R20: gather unrolled x8 (scalar col loads batched ahead of vector loads;
// FP accumulation order unchanged, index-ascending).
__global__ void k_gfin2(const float* __restrict__ r, const float* __restrict__ u,
                        const int* __restrict__ rowptr, const int* __restrict__ col,
                        const int* __restrict__ batch, const int* __restrict__ gP,
                        const int* __restrict__ nvP, float* __restrict__ h,
                        const float* __restrict__ pw, float* __restrict__ aN,
                        float* __restrict__ bN, float* __restrict__ xs_part /*[64][512]*/,
                        float* __restrict__ gn_part /*[64][8] or null*/, int n, int swz) {
  __shared__ float sacc[512];
  __shared__ float scnt8[8];
  __shared__ float pws[128];
  __shared__ int pres;
  int G = *gP;
  int nv = nvP ? *nvP : n;
  if (nv > n) nv = n;
  for (int i = threadIdx.x; i < 512; i += 256) sacc[i] = 0.f;
  if (threadIdx.x < 8) scnt8[threadIdx.x] = 0.f;
  if (threadIdx.x == 0) pres = 0;
  if (pw && threadIdx.x < 128) pws[threadIdx.x] = pw[threadIdx.x];
  __syncthreads();
  int b = blockIdx.x;
  if (swz) { int chunk = gridDim.x >> 3; b = (b & 7) * chunk + (b >> 3); }
  int lane = threadIdx.x & 63, w = threadIdx.x >> 6;
  int node = b * 4 + w;
  if (node < nv) {
    int bg = rowptr[node], e2 = rowptr[node + 1];
    float s = 0.f;
    int j = bg;
    for (; j + 8 <= e2; j += 8) {
      int c0 = col[j], c1 = col[j + 1], c2 = col[j + 2], c3 = col[j + 3];
      int c4 = col[j + 4], c5 = col[j + 5], c6 = col[j + 6], c7 = col[j + 7];
      float v0 = r[(size_t)c0 * 64 + lane];
      float v1 = r[(size_t)c1 * 64 + lane];
      float v2 = r[(size_t)c2 * 64 + lane];
      float v3 = r[(size_t)c3 * 64 + lane];
      float v4 = r[(size_t)c4 * 64 + lane];
      float v5 = r[(size_t)c5 * 64 + lane];
      float v6 = r[(size_t)c6 * 64 + lane];
      float v7 = r[(size_t)c7 * 64 + lane];
      s += v0; s += v1; s += v2; s += v3;
      s += v4; s += v5; s += v6; s += v7;
    }
    for (; j + 4 <= e2; j += 4) {
      int c0 = col[j], c1 = col[j + 1], c2 = col[j + 2], c3 = col[j + 3];
      float v0 = r[(size_t)c0 * 64 + lane];
      float v1 = r[(size_t)c1 * 64 + lane];
      float v2 = r[(size_t)c2 * 64 + lane];
      float v3 = r[(size_t)c3 * 64 + lane];
      s += v0; s += v1; s += v2; s += v3;
    }
    for (; j < e2; ++j) s += r[(size_t)col[j] * 64 + lane];
    int deg = e2 - bg;
    float inv = deg > 0 ? 1.f / (float)deg : 0.f;
    float v = fmaf(s, inv, u[(size_t)node * 64 + lane]);
    v = v > 0.f ? v : 0.f;
    h[(size_t)node * 64 + lane] = v;
    if (pw) {
      float d1 = v * pws[lane];
      float d2 = v * pws[64 + lane];
#pragma unroll
      for (int off = 32; off > 0; off >>= 1) {
        d1 += __shfl_down(d1, off, 64);
        d2 += __shfl_down(d2, off, 64);
      }
      if (lane == 0) { aN[node] = d1; bN[node] = d2; }
    }
    int g = batch[node];
    if ((unsigned)g < 8u && g < G) {
      atomicAdd(&sacc[g * 64 + lane], v);
      if (lane == 0) {
        atomicOr(&pres, 1 << g);
        if (gn_part) atomicAdd(&scnt8[g], 1.f);
      }
    }
  }
  __syncthreads();
  int pm = pres;
  if (!pm) return;
  int buf = blockIdx.x & 63;
  float* xp = xs_part + buf * 512;
  for (int i = threadIdx.x; i < 512; i += 256) {
    if ((pm >> (i >> 6)) & 1) {
      float s2 = sacc[i];
      if (s2 != 0.f) atomicAdd(&xp[i], s2);
    }
  }
  if (gn_part && threadIdx.x < 8) {
    float c = scnt8[threadIdx.x];
    if (c != 0.f) atomicAdd(&gn_part[buf * 8 + threadIdx.x], c);
  }
}

// R8/R9: CSR-ordered scoring + round-0 priority claim into global bcur0.
// R15: pass-1 expf cached in sdA[j].  R16: no score[] scatter (score bits
// travel in the key; recovered at match time).
__global__ void k_score_csr(const float* __restrict__ aN, const float* __restrict__ bN,
                            const float* __restrict__ pbp, const int* __restrict__ rowptr,
                            const int* __restrict__ col, const int* __restrict__ eid,
                            const int* __restrict__ gP,
                            u64* __restrict__ keyA, u32* __restrict__ sdA,
                            u64* __restrict__ bcur0, int N) {
  int d = blockIdx.x * blockDim.x + threadIdx.x;
  if (d >= N) return;
  int b = rowptr[d], e2 = rowptr[d + 1];
  if (b == e2) return;
  float bd = bN[d] + pbp[0];
  float den = 0.f;
  for (int j = b; j < e2; ++j) {
    float ex = expf(aN[col[j]] + bd);
    sdA[j] = __float_as_uint(ex);  // cache; overwritten in pass 2
    den += ex;
  }
  int per = N / *gP;
  int g = d / per;
  int base = g * per;
  u32 dl = (u32)(d - base);
  u64 rmin = ~0ull;
  for (int j = b; j < e2; ++j) {
    int s = col[j];
    int ei = eid[j];
    float ex = __uint_as_float(sdA[j]);
    float sc = ex / den + 0.5f;
    u64 k = ((u64)(u32)(~__float_as_uint(sc)) << 20) | (u32)ei;
    keyA[j] = k;
    sdA[j] = ((u32)(s - base) << 16) | dl;
    atomicMin(&bcur0[s], k);
    if (k < rmin) rmin = k;
  }
  atomicMin(&bcur0[d], rmin);
}

// R19: O(N) round-0 match test.  An edge matches iff it is the min key at
// both endpoints; the only candidate at node v is bcur0[v] itself, whose
// endpoints come from src/dst[eid].  bcur0 read-only -> deterministic.
__global__ void k_match0(const int* __restrict__ src, const int* __restrict__ dst,
                         const u64* __restrict__ bcur0, u32* __restrict__ matched,
                         u8* __restrict__ dead, int N) {
  int v = blockIdx.x * blockDim.x + threadIdx.x;
  if (v >= N) return;
  u64 k = bcur0[v];
  if (k == ~0ull) return;
  int ei = (int)(k & 0xFFFFF);
  int s = src[ei], d = dst[ei];
  if (bcur0[s] == k && bcur0[d] == k) {
    matched[ei] = ~((u32)(k >> 20));
    dead[s] = 1;
    dead[d] = 1;
  }
}

// R9: grid-wide alive-list build (dead stable/read-only here).
__global__ void k_list0(const int* __restrict__ rowptr, const int* __restrict__ gP,
                        const u64* __restrict__ keyA, const u32* __restrict__ sdA,
                        const u8* __restrict__ dead, u64* __restrict__ keyB,
                        u32* __restrict__ sdB, int* __restrict__ gposM, int N) {
  __shared__ int scnt[8], sbase[8];
  if (threadIdx.x < 8) scnt[threadIdx.x] = 0;
  __syncthreads();
  int d = blockIdx.x * blockDim.x + threadIdx.x;
  int g = -1, b = 0, e2 = 0, base = 0, myn = 0, rank = 0;
  if (d < N && !dead[d]) {
    b = rowptr[d]; e2 = rowptr[d + 1];
    if (b < e2) {
      int per = N / *gP;
      g = d / per; base = g * per;
      for (int j = b; j < e2; ++j)
        if (!dead[base + (int)(sdA[j] >> 16)]) ++myn;
      if (myn) rank = atomicAdd(&scnt[g], myn);
    }
  }
  __syncthreads();
  if (threadIdx.x < 8 && scnt[threadIdx.x])
    sbase[threadIdx.x] = atomicAdd(&gposM[threadIdx.x], scnt[threadIdx.x]);
  __syncthreads();
  if (g < 0 || !myn) return;
  int off = rowptr[base] + sbase[g] + rank;
  for (int j = b; j < e2; ++j) {
    if (!dead[base + (int)(sdA[j] >> 16)]) {
      keyB[off] = keyA[j];
      sdB[off] = sdA[j];
      ++off;
    }
  }
}

// Per-graph exact greedy matching from round 1.  (R16 form, measured 161us.)
// Big rounds (n > WAVECAP): global ping-pong with prefetch pipeline.
// n <= WAVECAP -> LDS-resident FULL-BLOCK rounds; nt <= 64 -> DAG solve.
// R19: Phase A global writes skipped when n <= WAVECAP (tail guaranteed).
#define PERMAX 12544
#define WAVECAP 2048
__global__ __launch_bounds__(1024) void k_match_wg(
    const int* __restrict__ rowptr, const int* __restrict__ gP,
    const int* __restrict__ gposM,
    u64* __restrict__ keyB, u64* __restrict__ keyA,
    u32* __restrict__ sdB, u32* __restrict__ sdA,
    u8* __restrict__ dead, u32* __restrict__ matched, int N) {
  __shared__ u64 bcur[PERMAX];
  __shared__ u8 dead_s[PERMAX];
  __shared__ u64 tkey[WAVECAP];
  __shared__ u32 tsd[WAVECAP];
  __shared__ u64 tkey2[WAVECAP];
  __shared__ u32 tsd2[WAVECAP];
  __shared__ int lcnt, lcnt2;
  int G = *gP;
  int g = blockIdx.x;
  if (g >= G) return;
  int per = N / G;
  if (per > PERMAX) per = PERMAX;
  int base = g * per;
  int re = rowptr[base];
  int n = gposM[g];
  int tid = threadIdx.x, lane = tid & 63;
  for (int i = tid; i < per; i += 1024) {
    bcur[i] = ~0ull;
    dead_s[i] = dead[base + i];
  }
  if (tid == 0) lcnt = 0;
  __syncthreads();
  u64* kin = keyB + re; u64* kout = keyA + re;
  u32* sin_ = sdB + re; u32* sout = sdA + re;
  for (int round = 1; n > 0 && round < 4000; ++round) {
    u64 etag = (u64)(4095 - round) << 52;
    bool skipg = (n <= WAVECAP);  // n2 <= n -> tail guaranteed, LDS suffices
    // Phase A: claim minima (fire-and-forget), ballot-compact, prefetched.
    u32 sd_p = 0; u64 k_p = 0;
    if (tid < n) { sd_p = sin_[tid]; k_p = kin[tid]; }
    for (int i = tid; i - lane < n; i += 1024) {
      bool inb = i < n;
      u32 sd = sd_p; u64 k = k_p;
      int inx = i + 1024;
      if (inx < n) { sd_p = sin_[inx]; k_p = kin[inx]; }
      int s = sd >> 16, d = sd & 0xffff;
      bool alive = inb && !(dead_s[s] | dead_s[d]);
      if (alive) {
        u64 val = etag | k;
        atomicMin(&bcur[s], val);
        if (d != s) atomicMin(&bcur[d], val);
      }
      u64 m = __ballot(alive);
      if (m) {
        int lead = __ffsll((long long)m) - 1;
        int bse = 0;
        if (lane == lead) bse = atomicAdd(&lcnt, __popcll(m));
        bse = __shfl(bse, lead, 64);
        if (alive) {
          int j = bse + __popcll(m & ((1ull << lane) - 1ull));
          if (!skipg) {
            kout[j] = k;
            sout[j] = sd;
          }
          if (j < WAVECAP) { tkey[j] = k; tsd[j] = sd; }
        }
      }
    }
    __syncthreads();
    int n2 = lcnt;
    if (n2 == 0) break;
    bool totail = (n2 <= WAVECAP);
    // Phase B: locally-dominant edges match (prefetched on global path)
    u32 sd_q = 0; u64 k_q = 0;
    if (!totail && tid < n2) { sd_q = sout[tid]; k_q = kout[tid]; }
    for (int i = tid; i < n2; i += 1024) {
      u32 sd; u64 k;
      if (totail) { sd = tsd[i]; k = tkey[i]; }
      else {
        sd = sd_q; k = k_q;
        int inx = i + 1024;
        if (inx < n2) { sd_q = sout[inx]; k_q = kout[inx]; }
      }
      int s = sd >> 16, d = sd & 0xffff;
      u64 val = etag | k;
      if (bcur[s] == val && (d == s || bcur[d] == val)) {
        matched[(u32)(k & 0xFFFFF)] = ~((u32)(k >> 20));
        dead_s[s] = 1;
        dead_s[d] = 1;
      }
    }
    if (tid == 0) lcnt = 0;
    __syncthreads();
    if (totail) {
      // ---- R14: LDS-resident full-block rounds (list <= WAVECAP) ----
      int nt = n2;
      int rr = round + 1;
      int cur = 0;
      while (nt > 64 && rr < 4000) {
        u64 et2 = (u64)(4095 - rr) << 52;
        u64* ks = cur ? tkey2 : tkey;
        u32* ss = cur ? tsd2 : tsd;
        u64* kd_ = cur ? tkey : tkey2;
        u32* sd_ = cur ? tsd : tsd2;
        int* cdst = cur ? &lcnt : &lcnt2;
        if (tid == 0) *cdst = 0;
        // claim pass
        for (int i = tid; i < nt; i += 1024) {
          u32 sd = ss[i];
          int s = sd >> 16, d = sd & 0xffff;
          if (dead_s[s] | dead_s[d]) continue;
          u64 val = et2 | ks[i];
          atomicMin(&bcur[s], val);
          if (d != s) atomicMin(&bcur[d], val);
        }
        __syncthreads();  // claims + cdst reset visible
        // fused test + compact into other buffer (order nondeterministic,
        // matching is key-determined -> result exact; dead_s races only
        // add stale entries, filtered by later alive-checks)
        for (int i = tid; i - lane < nt; i += 1024) {
          bool inb = i < nt;
          u32 sd = 0; u64 k = 0;
          if (inb) { sd = ss[i]; k = ks[i]; }
          int s = sd >> 16, d = sd & 0xffff;
          bool alive = false;
          if (inb && !(dead_s[s] | dead_s[d])) {
            u64 val = et2 | k;
            if (bcur[s] == val && (d == s || bcur[d] == val)) {
              matched[(u32)(k & 0xFFFFF)] = ~((u32)(k >> 20));
              dead_s[s] = 1;
              dead_s[d] = 1;
            } else {
              alive = true;
            }
          }
          u64 m = __ballot(alive);
          if (m) {
            int lead = __ffsll((long long)m) - 1;
            int bse = 0;
            if (lane == lead) bse = atomicAdd(cdst, __popcll(m));
            bse = __shfl(bse, lead, 64);
            if (alive) {
              int j = bse + __popcll(m & ((1ull << lane) - 1ull));
              kd_[j] = k;
              sd_[j] = sd;
            }
          }
        }
        __syncthreads();  // deaths + appends complete
        nt = cur ? lcnt : lcnt2;
        cur ^= 1;
        ++rr;
      }
      if (nt > 0) {
        if (tid < 64) {
          // ---- one-shot exact greedy over <=64 edges (single wave) ----
          // list may contain stale-dead entries -> re-check dead_s (list
          // and dead_s are stable here: barrier above).
          u64* ks = cur ? tkey2 : tkey;
          u32* ss = cur ? tsd2 : tsd;
          u64 myk = 0; u32 mysd = 0;
          bool have = lane < nt;
          if (have) { myk = ks[lane]; mysd = ss[lane]; }
          int ms = mysd >> 16, md = mysd & 0xffff;
          if (have && (dead_s[ms] | dead_s[md])) have = false;
          u64 C = 0;
          for (int j = 0; j < nt; ++j) {
            int js = __shfl(ms, j, 64);
            int jd = __shfl(md, j, 64);
            u64 jk = __shfl(myk, j, 64);
            int jh = __shfl((int)have, j, 64);
            bool conf = have && jh && j != lane && jk < myk &&
                        (js == ms || js == md || jd == ms || jd == md);
            if (conf) C |= 1ull << j;
          }
          u64 undec = __ballot(have);
          u64 M = 0;
          while (undec) {
            bool rdy = have && ((undec >> lane) & 1ull) && (C & undec) == 0;
            bool mt = rdy && (C & M) == 0;
            u64 rdym = __ballot(rdy);
            u64 mm = __ballot(mt);
            M |= mm;
            undec &= ~rdym;
            if (!rdym) break;  // safety: DAG guarantees progress
          }
          if (have && ((M >> lane) & 1ull)) {
            matched[(u32)(myk & 0xFFFFF)] = ~((u32)(myk >> 20));
            dead_s[ms] = 1;
            dead_s[md] = 1;
          }
        }
        __syncthreads();
      }
      break;
    }
    u64* tk = kin; kin = kout; kout = tk;
    u32* ts = sin_; sin_ = sout; sout = ts;
    n = n2;
  }
  __syncthreads();
  for (int i = tid; i < per; i += 1024) dead[base + i] = dead_s[i];
}

// R7 two-phase cluster build (512 blocks); also zeroes cnt.
// R16: matched carries score bits -> per-cluster gsc.
__global__ void k_build2(const u32* __restrict__ matched, const int* __restrict__ src,
                         const int* __restrict__ dst, const int* __restrict__ batch,
                         const u8* __restrict__ dead, int* __restrict__ cluster,
                         int* __restrict__ new_batch, int* __restrict__ srcE,
                         float* __restrict__ gsc,
                         int* __restrict__ nclus, float* __restrict__ gccnt,
                         int* __restrict__ cnt, int e, int n, int nc) {
  __shared__ int c_cnt, c_off, basep;
  __shared__ int sc[8];
  if (threadIdx.x == 0) { c_cnt = 0; c_off = 0; basep = 0; }
  if (threadIdx.x < 8) sc[threadIdx.x] = 0;
  __syncthreads();
  int nbk = gridDim.x;
  for (int i = blockIdx.x * blockDim.x + threadIdx.x; i < nc; i += nbk * blockDim.x) cnt[i] = 0;
  int ec = (e + nbk - 1) / nbk, es = blockIdx.x * ec, ee = es + ec; if (ee > e) ee = e;
  int nk = (n + nbk - 1) / nbk, ns = blockIdx.x * nk, ne = ns + nk; if (ne > n) ne = n;
  int my = 0;
  for (int i = es + threadIdx.x; i < ee; i += blockDim.x) if (matched[i]) ++my;
  for (int i = ns + threadIdx.x; i < ne; i += blockDim.x) if (!dead[i]) ++my;
  if (my) atomicAdd(&c_cnt, my);
  __syncthreads();
  if (threadIdx.x == 0 && c_cnt) basep = atomicAdd(nclus, c_cnt);
  __syncthreads();
  int bse = basep;
  for (int i = es + threadIdx.x; i < ee; i += blockDim.x) {
    u32 m = matched[i];
    if (!m) continue;
    int c = bse + atomicAdd(&c_off, 1);
    int s = src[i], d = dst[i];
    cluster[s] = c;
    cluster[d] = c;
    srcE[c] = i;
    gsc[c] = __uint_as_float(m);
    int g = batch[s];
    new_batch[c] = g;
    if ((unsigned)g < 8u) atomicAdd(&sc[g], 1);
  }
  for (int i = ns + threadIdx.x; i < ne; i += blockDim.x) {
    if (dead[i]) continue;
    int c = bse + atomicAdd(&c_off, 1);
    cluster[i] = c;
    srcE[c] = ~i;  // singleton: encoded node
    gsc[c] = 1.0f;
    int g = batch[i];
    new_batch[c] = g;
    if ((unsigned)g < 8u) atomicAdd(&sc[g], 1);
  }
  __syncthreads();
  if (threadIdx.x < 8 && sc[threadIdx.x] > 0)
    atomicAdd(&gccnt[threadIdx.x], (float)sc[threadIdx.x]);
}

#define HBITS 21
#define HMASK ((1u << HBITS) - 1u)

// cluster-driven new_x (wave per cluster) + hash-table init prologue.
// R16: score via per-cluster gsc (coalesced) instead of random score[eid].
__global__ void k_newx(const int* __restrict__ srcE, const int* __restrict__ src,
                       const int* __restrict__ dst, const float* __restrict__ gsc,
                       const int* __restrict__ nclusP, const float* __restrict__ h2,
                       float* __restrict__ new_x, u64* __restrict__ table, int n) {
  int idx = blockIdx.x * blockDim.x + threadIdx.x;
  if (idx < (1 << HBITS)) table[idx] = ~0ull;
  int c = idx >> 6;
  int lane = idx & 63;
  if (c >= n || c >= *nclusP) return;
  int v = srcE[c];
  float val;
  if (v >= 0) {
    int s = src[v], d = dst[v];
    val = h2[(size_t)s * 64 + lane];
    if (d != s) val += h2[(size_t)d * 64 + lane];
    val *= gsc[c];
  } else {
    val = h2[(size_t)(~v) * 64 + lane];
  }
  new_x[(size_t)c * 64 + lane] = val;
}

// coalesce(cluster[edge_index]): hash-dedup; dups -> sentinel n; counts kept.
__global__ void k_dedup(const int* __restrict__ src, const int* __restrict__ dst,
                        const int* __restrict__ cluster, u64* __restrict__ table,
                        int* __restrict__ ns, int* __restrict__ nd,
                        int* __restrict__ cnt, int e, int n) {
  int i = blockIdx.x * blockDim.x + threadIdx.x;
  if (i >= e) return;
  int cs_ = cluster[src[i]], cd_ = cluster[dst[i]];
  u64 kk = (u64)cs_ * (u64)(n + 1) + (u64)cd_;
  u32 pos = (u32)((kk * 0x9E3779B97F4A7C15ull) >> 43) & HMASK;
  while (true) {
    u64 old = atomicCAS(&table[pos], ~0ull, kk);
    if (old == ~0ull) {
      ns[i] = cs_; nd[i] = cd_;
      atomicAdd(&cnt[cd_], 1);
      return;
    }
    if (old == kk) { ns[i] = n; nd[i] = n; return; }
    pos = (pos + 1) & HMASK;
  }
}

// JK cat (partial-buffer reduce) + lin1 + relu + lin2 + log_softmax.
// R16: one block per graph (was 1 block total).  FP order identical.
__global__ void k_head(const float* __restrict__ xs_part /*[4][64][512]*/,
                       const float* __restrict__ gn_part /*[64][8]*/,
                       const float* __restrict__ gccnt,
                       const float* __restrict__ l1w, const float* __restrict__ l1b,
                       const float* __restrict__ l2w, const float* __restrict__ l2b,
                       const int* __restrict__ gP, float* __restrict__ out, int C) {
  __shared__ float z[256];
  __shared__ float z1[64];
  __shared__ float z2[16];
  __shared__ float gnc;
  int G = *gP;
  int g = blockIdx.x;
  if (g >= G) return;
  int tid = threadIdx.x;
  if (tid < 64) {
    float s = gn_part[tid * 8 + g];
#pragma unroll
    for (int off = 32; off > 0; off >>= 1) s += __shfl_down(s, off, 64);
    if (tid == 0) gnc = s;
  }
  __syncthreads();
  {
    int p = tid >> 6, f = tid & 63;
    const float* xp = xs_part + (size_t)p * 64 * 512;
    float s = 0.f;
    for (int b = 0; b < 64; ++b) s += xp[b * 512 + g * 64 + f];
    float c = (p < 2) ? gnc : gccnt[g];
    if (c < 1.f) c = 1.f;
    z[tid] = s / c;
  }
  __syncthreads();
  if (tid < 64) {
    int o = tid;
    float a = l1b[o];
    for (int k = 0; k < 256; ++k) a = fmaf(z[k], l1w[o * 256 + k], a);
    z1[o] = a > 0.f ? a : 0.f;
  }
  __syncthreads();
  if (tid < C) {
    int c = tid;
    float a = l2b[c];
    for (int k = 0; k < 64; ++k) a = fmaf(z1[k], l2w[c * 64 + k], a);
    z2[c] = a;
  }
  __syncthreads();
  if (tid == 0) {
    float m = z2[0];
    for (int c = 1; c < C; ++c) m = fmaxf(m, z2[c]);
    float s = 0.f;
    for (int c = 0; c < C; ++c) s += expf(z2[c] - m);
    float lse = m + logf(s);
    for (int c = 0; c < C; ++c) out[g * C + c] = z2[c] - lse;
  }
}

extern "C" void kernel_launch(void* const* d_in, const int* in_sizes, int n_in,
                              void* d_out, int out_size, void* d_ws, size_t ws_size,
                              hipStream_t stream) {
  const float* x       = (const float*)d_in[0];
  const int*   ei      = (const int*)d_in[1];
  const int*   batch   = (const int*)d_in[2];
  const float* w_rel1  = (const float*)d_in[3];
  const float* b_rel1  = (const float*)d_in[4];
  const float* w_root1 = (const float*)d_in[5];
  const float* w_rel2  = (const float*)d_in[6];
  const float* b_rel2  = (const float*)d_in[7];
  const float* w_root2 = (const float*)d_in[8];
  const float* w_rel3  = (const float*)d_in[9];
  const float* b_rel3  = (const float*)d_in[10];
  const float* w_root3 = (const float*)d_in[11];
  const float* w_rel4  = (const float*)d_in[12];
  const float* b_rel4  = (const float*)d_in[13];
  const float* w_root4 = (const float*)d_in[14];
  const float* pool_w  = (const float*)d_in[15];
  const float* pool_b  = (const float*)d_in[16];
  const float* lin1_w  = (const float*)d_in[17];
  const float* lin1_b  = (const float*)d_in[18];
  const float* lin2_w  = (const float*)d_in[19];
  const float* lin2_b  = (const float*)d_in[20];
  const int*   gP      = (const int*)d_in[21];
  float* out = (float*)d_out;

  const int N = in_sizes[2];
  const int E = in_sizes[1] / 2;
  const int C = in_sizes[20];
  const int* src = ei;
  const int* dst = ei + E;

  // ---- workspace layout ----
  char* w = (char*)d_ws;
  auto alloc = [&](size_t bytes) -> char* {
    char* p = w;
    w += (bytes + 255) & ~(size_t)255;
    return p;
  };
  float* r      = (float*)alloc((size_t)N * 64 * 4);
  float* agg    = (float*)alloc((size_t)(N + 1) * 64 * 4);  // u / match lists / hash
  float* hA     = (float*)alloc((size_t)N * 64 * 4);        // h1 -> new_x -> h4
  float* hB     = (float*)alloc((size_t)N * 64 * 4);        // h2 -> h3
  float* gsc    = (float*)alloc((size_t)(N + 2) * 4);       // per-cluster score
  int*   colbuf = (int*)alloc((size_t)E * 8);               // col + eid
  int*   listA  = (int*)alloc((size_t)E * 4);               // aN -> ns
  int*   listB  = (int*)alloc((size_t)E * 4);               // bN -> nd
  int*   rowptr = (int*)alloc((size_t)(N + 2) * 4);
  int*   pos    = (int*)alloc((size_t)(N + 2) * 4);         // also srcE
  char* zstart = w;                                         // zeroed block
  int*   cnt       = (int*)alloc((size_t)(N + 2) * 4);
  int*   scanfl    = (int*)alloc(2 * 384 * 4);              // 2x lookback flag sets
  u8*    dead      = (u8*)alloc((size_t)N);
  u32*   matched   = (u32*)alloc((size_t)E * 4);            // score bits or 0
  int*   cluster   = (int*)alloc((size_t)N * 4);
  int*   new_batch = (int*)alloc((size_t)N * 4);
  float* xs_part   = (float*)alloc((size_t)4 * 64 * 512 * 4);  // per-stage partials
  float* gn_part   = (float*)alloc((size_t)64 * 8 * 4);
  float* small     = (float*)alloc(16384);
  size_t zbytes = (size_t)(w - zstart);
  if ((size_t)(w - (char*)d_ws) > ws_size) return;  // fail loudly

  int*   col = colbuf;         // CSR src per slot
  int*   eid = colbuf + E;     // CSR original-edge id per slot
  float* aN  = (float*)listA;  // alias: dots dead before ns/nd used
  float* bN  = (float*)listB;
  float* uB  = agg;            // u for all convs (agg phase-disjoint)
  u64*   keyA = (u64*)agg;     // score/key output + match ping-pong
  u64*   keyB = keyA + E;
  u32*   sdA  = (u32*)(keyB + E);
  u32*   sdB  = sdA + E;
  u64*   bcur0 = (u64*)(sdB + E);  // round-0 global minima (tail of agg)
  u64*   table = (u64*)agg;    // hash (after match, before conv3)
  int*   srcE = pos;           // alias: pos re-filled later by 2nd scan_out

  float* gccnt  = small;                 // [8]
  int*   nclusP = (int*)(small + 16);
  int*   gposM  = (int*)(small + 32);    // [8] alive-list counters (zeroed)

  const int TB = 256;
  const int chunks = (((N + 511) / 512) + 7) & ~7;  // %8==0 for XCD grouping
  const int gT = chunks * 4;                        // x: {xcd, oq, chunk}
  const int gN = (N + TB - 1) / TB;
  const int gE = (E + TB - 1) / TB;
  const int gE1k = (E + 1023) >> 10;
  const int gNw = (int)(((size_t)N * 64 + TB - 1) / TB);  // wave per node
  const int swz = (gNw % 8 == 0) ? 1 : 0;
  const int nc = N + 2;
  const int nb = (nc + 1023) / 1024;

  hipMemsetAsync(zstart, 0, zbytes, stream);

  // ---- CSR for original edges ----
  k_count<<<gE1k, TB, 0, stream>>>(dst, cnt, E);
  k_scan<<<nb, TB, 0, stream>>>(cnt, rowptr, pos, scanfl, nc);
  k_fill<<<gE, TB, 0, stream>>>(src, dst, pos, col, eid, bcur0, N, E, N);

  // ---- conv1 (F=128 -> 64) ----
  k_transform2<128><<<gT, TB, 0, stream>>>(x, w_rel1, w_root1, b_rel1, nullptr, r, uB, N);
  k_gfin2<<<gNw, TB, 0, stream>>>(r, uB, rowptr, col, batch, gP, nullptr, hA,
                                  nullptr, nullptr, nullptr, xs_part + 0 * 32768, gn_part, N, swz);

  // ---- conv2 (64 -> 64, + score dots) ----
  k_transform2<64><<<gT, TB, 0, stream>>>(hA, w_rel2, w_root2, b_rel2, nullptr, r, uB, N);
  k_gfin2<<<gNw, TB, 0, stream>>>(r, uB, rowptr, col, batch, gP, nullptr, hB,
                                  pool_w, aN, bN, xs_part + 1 * 32768, nullptr, N, swz);

  // ---- scoring (CSR order) + grid-wide matching round 0 ----
  k_score_csr<<<gN, TB, 0, stream>>>(aN, bN, pool_b, rowptr, col, eid, gP,
                                     keyA, sdA, bcur0, N);
  k_match0<<<gN, TB, 0, stream>>>(src, dst, bcur0, matched, dead, N);
  k_list0<<<gN, TB, 0, stream>>>(rowptr, gP, keyA, sdA, dead, keyB, sdB, gposM, N);

  // ---- greedy matching rounds 1+ (per-graph WG, LDS state, LDS tail) ----
  k_match_wg<<<8, 1024, 0, stream>>>(rowptr, gP, gposM, keyB, keyA, sdB, sdA,
                                     dead, matched, N);

  // ---- clusters (two-phase), new_x (+hash init), dedup + pooled CSR ----
  k_build2<<<512, TB, 0, stream>>>(matched, src, dst, batch, dead, cluster, new_batch,
                                   srcE, gsc, nclusP, gccnt, cnt, E, N, nc);
  k_newx<<<gNw, TB, 0, stream>>>(srcE, src, dst, gsc, nclusP, hB, hA, table, N);
  k_dedup<<<gE, TB, 0, stream>>>(src, dst, cluster, table, listA, listB, cnt, E, N);
  k_scan<<<nb, TB, 0, stream>>>(cnt, rowptr, pos, scanfl + 384, nc);
  k_fill<<<gE, TB, 0, stream>>>(listA, listB, pos, col, nullptr, nullptr, 0, E, N);

  // ---- conv3 (64 -> 64, pooled) ----
  k_transform2<64><<<gT, TB, 0, stream>>>(hA, w_rel3, w_root3, b_rel3, nclusP, r, uB, N);
  k_gfin2<<<gNw, TB, 0, stream>>>(r, uB, rowptr, col, new_batch, gP, nclusP, hB,
                                  nullptr, nullptr, nullptr, xs_part + 2 * 32768, nullptr, N, 0);

  // ---- conv4 (64 -> 64, pooled) ----
  k_transform2<64><<<gT, TB, 0, stream>>>(hB, w_rel4, w_root4, b_rel4, nclusP, r, uB, N);
  k_gfin2<<<gNw, TB, 0, stream>>>(r, uB, rowptr, col, new_batch, gP, nclusP, hA,
                                  nullptr, nullptr, nullptr, xs_part + 3 * 32768, nullptr, N, 0);

  // ---- head ----
  k_head<<<8, TB, 0, stream>>>(xs_part, gn_part, gccnt, lin1_w, lin1_b, lin2_w, lin2_b, gP, out, C);
}

// Round 12
// 1078.142 us; speedup vs baseline: 1.0488x; 1.0488x over previous
//
#include <hip/hip_runtime.h>
#include <stdint.h>

typedef unsigned long long u64;
typedef unsigned int u32;
typedef unsigned char u8;

// ---------------------------------------------------------------------------
// EdgePool GNN pipeline.  N=100000, E=800000, F=128, H=64, G=8, C=10. f32.
// R1 two-stage gmp · R2 dst-CSR gather · R4 match state in LDS · R5 XCD
// swizzle + epoch bcur + no-max softmax · R7 wave-per-node gfin2 + partial
// gmp flush + two-phase build · R8 CSR-ordered scoring · R9 grid-wide
// matching round 0 · R14 LDS-resident match mid-tail · R16 prefetch +
// score-in-key + per-graph head · R18 gfin2 unroll + fused scan · R19
// O(N) match0 · R20 2-node o-quarter transform + gfin2 x8 + u8 dead.
// R22: R21's decoupled-lookback scan REVERTED — its lookback walk is
//      serial in one thread (up to 97 global-atomic round-trips ~25us per
//      site) and cost more than the 2 launches it saved (1080->1131).
//      Back to the proven scan_sums + scan_out pair (R18 form). The
//      bcur0-init fold into k_fill is kept (benign: one coalesced store
//      per thread, saves a memset launch).
// ---------------------------------------------------------------------------

// 1D grid = chunks*4, chunks % 8 == 0.  bid -> {xcd=bid&7, oq=(bid>>3)&3,
// chunk=(bid>>5)*8+xcd}: a chunk's 4 o-quarter blocks share an XCD.
template <int K>
__global__ __launch_bounds__(256) void k_transform2(
    const float* __restrict__ x, const float* __restrict__ wrel,
    const float* __restrict__ wroot, const float* __restrict__ bias,
    const int* __restrict__ nvP, float* __restrict__ r,
    float* __restrict__ u, int n) {
  __shared__ float wsR[16 * K];
  __shared__ float wsU[16 * K];
  int xcd = blockIdx.x & 7;
  int s = blockIdx.x >> 3;
  int oq = s & 3;
  int chunk = (s >> 2) * 8 + xcd;
  const int ob = oq * 16;
  const float* __restrict__ wA = wrel + (size_t)ob * K;
  const float* __restrict__ wB = wroot + (size_t)ob * K;
  for (int i = threadIdx.x; i < 4 * K; i += 256) {
    reinterpret_cast<float4*>(wsR)[i] = reinterpret_cast<const float4*>(wA)[i];
    reinterpret_cast<float4*>(wsU)[i] = reinterpret_cast<const float4*>(wB)[i];
  }
  int nv = n;
  if (nvP) { int v = *nvP; if (v < nv) nv = v; }
  int node0 = chunk * 512 + threadIdx.x;
  int node1 = node0 + 256;
  bool act0 = node0 < nv;
  bool act1 = node1 < nv;
  __syncthreads();
  if (!(act0 | act1)) return;
  // clamp inactive rows to row 0: harmless reads, writes guarded below
  const float* xr0 = x + (size_t)(act0 ? node0 : 0) * K;
  const float* xr1 = x + (size_t)(act1 ? node1 : 0) * K;
  float aR0[16], aU0[16], aR1[16], aU1[16];
#pragma unroll
  for (int o = 0; o < 16; ++o) {
    float b = bias[ob + o];
    aR0[o] = 0.f; aR1[o] = 0.f;
    aU0[o] = b;   aU1[o] = b;
  }
  for (int k = 0; k < K; k += 4) {
    float4 xv0 = *reinterpret_cast<const float4*>(xr0 + k);
    float4 xv1 = *reinterpret_cast<const float4*>(xr1 + k);
#pragma unroll
    for (int o = 0; o < 16; ++o) {
      float4 wv = *reinterpret_cast<const float4*>(&wsR[o * K + k]);
      aR0[o] = fmaf(xv0.x, wv.x, aR0[o]);
      aR0[o] = fmaf(xv0.y, wv.y, aR0[o]);
      aR0[o] = fmaf(xv0.z, wv.z, aR0[o]);
      aR0[o] = fmaf(xv0.w, wv.w, aR0[o]);
      aR1[o] = fmaf(xv1.x, wv.x, aR1[o]);
      aR1[o] = fmaf(xv1.y, wv.y, aR1[o]);
      aR1[o] = fmaf(xv1.z, wv.z, aR1[o]);
      aR1[o] = fmaf(xv1.w, wv.w, aR1[o]);
      float4 wu = *reinterpret_cast<const float4*>(&wsU[o * K + k]);
      aU0[o] = fmaf(xv0.x, wu.x, aU0[o]);
      aU0[o] = fmaf(xv0.y, wu.y, aU0[o]);
      aU0[o] = fmaf(xv0.z, wu.z, aU0[o]);
      aU0[o] = fmaf(xv0.w, wu.w, aU0[o]);
      aU1[o] = fmaf(xv1.x, wu.x, aU1[o]);
      aU1[o] = fmaf(xv1.y, wu.y, aU1[o]);
      aU1[o] = fmaf(xv1.z, wu.z, aU1[o]);
      aU1[o] = fmaf(xv1.w, wu.w, aU1[o]);
    }
  }
  if (act0) {
    float4* op = reinterpret_cast<float4*>(r + (size_t)node0 * 64 + ob);
#pragma unroll
    for (int o = 0; o < 4; ++o)
      op[o] = make_float4(aR0[4 * o], aR0[4 * o + 1], aR0[4 * o + 2], aR0[4 * o + 3]);
    op = reinterpret_cast<float4*>(u + (size_t)node0 * 64 + ob);
#pragma unroll
    for (int o = 0; o < 4; ++o)
      op[o] = make_float4(aU0[4 * o], aU0[4 * o + 1], aU0[4 * o + 2], aU0[4 * o + 3]);
  }
  if (act1) {
    float4* op = reinterpret_cast<float4*>(r + (size_t)node1 * 64 + ob);
#pragma unroll
    for (int o = 0; o < 4; ++o)
      op[o] = make_float4(aR1[4 * o], aR1[4 * o + 1], aR1[4 * o + 2], aR1[4 * o + 3]);
    op = reinterpret_cast<float4*>(u + (size_t)node1 * 64 + ob);
#pragma unroll
    for (int o = 0; o < 4; ++o)
      op[o] = make_float4(aU1[4 * o], aU1[4 * o + 1], aU1[4 * o + 2], aU1[4 * o + 3]);
  }
}

// dst-degree count; 1024-edge chunks
__global__ void k_count(const int* __restrict__ dst, int* __restrict__ cnt, int e) {
  int base = blockIdx.x << 10;
#pragma unroll
  for (int k = 0; k < 4; ++k) {
    int i = base + k * 256 + threadIdx.x;
    if (i < e) atomicAdd(&cnt[dst[i]], 1);
  }
}

// ---- scan over nc ints (2 kernels; scan_out folds the block-sum prefix) ----
__global__ void k_scan_sums(const int* __restrict__ in, int* __restrict__ bsum, int n) {
  __shared__ int sd[256];
  int base = blockIdx.x << 10;
  int s = 0;
  for (int j = threadIdx.x; j < 1024; j += 256) {
    int id = base + j;
    s += (id < n) ? in[id] : 0;
  }
  sd[threadIdx.x] = s;
  __syncthreads();
  for (int w = 128; w > 0; w >>= 1) {
    if (threadIdx.x < w) sd[threadIdx.x] += sd[threadIdx.x + w];
    __syncthreads();
  }
  if (threadIdx.x == 0) bsum[blockIdx.x] = sd[0];
}
__global__ void k_scan_out(const int* __restrict__ in, const int* __restrict__ bsum,
                           int* __restrict__ rowptr, int* __restrict__ pos, int n, int nb) {
  __shared__ int sd[256];
  __shared__ int sb[256];
  for (int i = threadIdx.x; i < 256; i += 256) sb[i] = (i < nb) ? bsum[i] : 0;
  int base = blockIdx.x << 10;
  int i0 = base + threadIdx.x * 4;
  int v0 = 0, v1 = 0, v2 = 0, v3 = 0;
  if (i0 < n) v0 = in[i0];
  if (i0 + 1 < n) v1 = in[i0 + 1];
  if (i0 + 2 < n) v2 = in[i0 + 2];
  if (i0 + 3 < n) v3 = in[i0 + 3];
  sd[threadIdx.x] = v0 + v1 + v2 + v3;
  __syncthreads();
  for (int off = 1; off < 256; off <<= 1) {
    int add = (threadIdx.x >= off) ? sd[threadIdx.x - off] : 0;
    __syncthreads();
    sd[threadIdx.x] += add;
    __syncthreads();
  }
  int basev = 0;
  for (int b2 = 0; b2 < blockIdx.x; ++b2) basev += sb[b2];
  int excl = basev + (threadIdx.x ? sd[threadIdx.x - 1] : 0);
  if (i0 < n) { rowptr[i0] = excl; pos[i0] = excl; }
  excl += v0;
  if (i0 + 1 < n) { rowptr[i0 + 1] = excl; pos[i0 + 1] = excl; }
  excl += v1;
  if (i0 + 2 < n) { rowptr[i0 + 2] = excl; pos[i0 + 2] = excl; }
  excl += v2;
  if (i0 + 3 < n) { rowptr[i0 + 3] = excl; pos[i0 + 3] = excl; }
}

// CSR fill: col = src, eid = original edge index.
// R21: optionally ~0-inits bcur0 (folds a memset launch; i<nb0 threads).
__global__ void k_fill(const int* __restrict__ src, const int* __restrict__ dst,
                       int* __restrict__ pos, int* __restrict__ col,
                       int* __restrict__ eid, u64* __restrict__ bc0, int nb0,
                       int e, int n) {
  int i = blockIdx.x * blockDim.x + threadIdx.x;
  if (i >= e) return;
  if (bc0 && i < nb0) bc0[i] = ~0ull;
  int d = dst[i];
  if (d >= n) return;  // sentinel (pooled duplicates)
  int j = atomicAdd(&pos[d], 1);
  col[j] = src[i];
  if (eid) eid[j] = i;
}

// R7 fused conv tail: wave-per-node gather + mean + relu + h-write (+dots),
// gmp accumulated in LDS, flushed to 64 partial buffers (presence-masked).
// R20: gather unrolled x8 (scalar col loads batched ahead of vector loads;
// FP accumulation order unchanged, index-ascending).
__global__ void k_gfin2(const float* __restrict__ r, const float* __restrict__ u,
                        const int* __restrict__ rowptr, const int* __restrict__ col,
                        const int* __restrict__ batch, const int* __restrict__ gP,
                        const int* __restrict__ nvP, float* __restrict__ h,
                        const float* __restrict__ pw, float* __restrict__ aN,
                        float* __restrict__ bN, float* __restrict__ xs_part /*[64][512]*/,
                        float* __restrict__ gn_part /*[64][8] or null*/, int n, int swz) {
  __shared__ float sacc[512];
  __shared__ float scnt8[8];
  __shared__ float pws[128];
  __shared__ int pres;
  int G = *gP;
  int nv = nvP ? *nvP : n;
  if (nv > n) nv = n;
  for (int i = threadIdx.x; i < 512; i += 256) sacc[i] = 0.f;
  if (threadIdx.x < 8) scnt8[threadIdx.x] = 0.f;
  if (threadIdx.x == 0) pres = 0;
  if (pw && threadIdx.x < 128) pws[threadIdx.x] = pw[threadIdx.x];
  __syncthreads();
  int b = blockIdx.x;
  if (swz) { int chunk = gridDim.x >> 3; b = (b & 7) * chunk + (b >> 3); }
  int lane = threadIdx.x & 63, w = threadIdx.x >> 6;
  int node = b * 4 + w;
  if (node < nv) {
    int bg = rowptr[node], e2 = rowptr[node + 1];
    float s = 0.f;
    int j = bg;
    for (; j + 8 <= e2; j += 8) {
      int c0 = col[j], c1 = col[j + 1], c2 = col[j + 2], c3 = col[j + 3];
      int c4 = col[j + 4], c5 = col[j + 5], c6 = col[j + 6], c7 = col[j + 7];
      float v0 = r[(size_t)c0 * 64 + lane];
      float v1 = r[(size_t)c1 * 64 + lane];
      float v2 = r[(size_t)c2 * 64 + lane];
      float v3 = r[(size_t)c3 * 64 + lane];
      float v4 = r[(size_t)c4 * 64 + lane];
      float v5 = r[(size_t)c5 * 64 + lane];
      float v6 = r[(size_t)c6 * 64 + lane];
      float v7 = r[(size_t)c7 * 64 + lane];
      s += v0; s += v1; s += v2; s += v3;
      s += v4; s += v5; s += v6; s += v7;
    }
    for (; j + 4 <= e2; j += 4) {
      int c0 = col[j], c1 = col[j + 1], c2 = col[j + 2], c3 = col[j + 3];
      float v0 = r[(size_t)c0 * 64 + lane];
      float v1 = r[(size_t)c1 * 64 + lane];
      float v2 = r[(size_t)c2 * 64 + lane];
      float v3 = r[(size_t)c3 * 64 + lane];
      s += v0; s += v1; s += v2; s += v3;
    }
    for (; j < e2; ++j) s += r[(size_t)col[j] * 64 + lane];
    int deg = e2 - bg;
    float inv = deg > 0 ? 1.f / (float)deg : 0.f;
    float v = fmaf(s, inv, u[(size_t)node * 64 + lane]);
    v = v > 0.f ? v : 0.f;
    h[(size_t)node * 64 + lane] = v;
    if (pw) {
      float d1 = v * pws[lane];
      float d2 = v * pws[64 + lane];
#pragma unroll
      for (int off = 32; off > 0; off >>= 1) {
        d1 += __shfl_down(d1, off, 64);
        d2 += __shfl_down(d2, off, 64);
      }
      if (lane == 0) { aN[node] = d1; bN[node] = d2; }
    }
    int g = batch[node];
    if ((unsigned)g < 8u && g < G) {
      atomicAdd(&sacc[g * 64 + lane], v);
      if (lane == 0) {
        atomicOr(&pres, 1 << g);
        if (gn_part) atomicAdd(&scnt8[g], 1.f);
      }
    }
  }
  __syncthreads();
  int pm = pres;
  if (!pm) return;
  int buf = blockIdx.x & 63;
  float* xp = xs_part + buf * 512;
  for (int i = threadIdx.x; i < 512; i += 256) {
    if ((pm >> (i >> 6)) & 1) {
      float s2 = sacc[i];
      if (s2 != 0.f) atomicAdd(&xp[i], s2);
    }
  }
  if (gn_part && threadIdx.x < 8) {
    float c = scnt8[threadIdx.x];
    if (c != 0.f) atomicAdd(&gn_part[buf * 8 + threadIdx.x], c);
  }
}

// R8/R9: CSR-ordered scoring + round-0 priority claim into global bcur0.
// R15: pass-1 expf cached in sdA[j].  R16: no score[] scatter (score bits
// travel in the key; recovered at match time).
__global__ void k_score_csr(const float* __restrict__ aN, const float* __restrict__ bN,
                            const float* __restrict__ pbp, const int* __restrict__ rowptr,
                            const int* __restrict__ col, const int* __restrict__ eid,
                            const int* __restrict__ gP,
                            u64* __restrict__ keyA, u32* __restrict__ sdA,
                            u64* __restrict__ bcur0, int N) {
  int d = blockIdx.x * blockDim.x + threadIdx.x;
  if (d >= N) return;
  int b = rowptr[d], e2 = rowptr[d + 1];
  if (b == e2) return;
  float bd = bN[d] + pbp[0];
  float den = 0.f;
  for (int j = b; j < e2; ++j) {
    float ex = expf(aN[col[j]] + bd);
    sdA[j] = __float_as_uint(ex);  // cache; overwritten in pass 2
    den += ex;
  }
  int per = N / *gP;
  int g = d / per;
  int base = g * per;
  u32 dl = (u32)(d - base);
  u64 rmin = ~0ull;
  for (int j = b; j < e2; ++j) {
    int s = col[j];
    int ei = eid[j];
    float ex = __uint_as_float(sdA[j]);
    float sc = ex / den + 0.5f;
    u64 k = ((u64)(u32)(~__float_as_uint(sc)) << 20) | (u32)ei;
    keyA[j] = k;
    sdA[j] = ((u32)(s - base) << 16) | dl;
    atomicMin(&bcur0[s], k);
    if (k < rmin) rmin = k;
  }
  atomicMin(&bcur0[d], rmin);
}

// R19: O(N) round-0 match test.  An edge matches iff it is the min key at
// both endpoints; the only candidate at node v is bcur0[v] itself, whose
// endpoints come from src/dst[eid].  bcur0 read-only -> deterministic.
__global__ void k_match0(const int* __restrict__ src, const int* __restrict__ dst,
                         const u64* __restrict__ bcur0, u32* __restrict__ matched,
                         u8* __restrict__ dead, int N) {
  int v = blockIdx.x * blockDim.x + threadIdx.x;
  if (v >= N) return;
  u64 k = bcur0[v];
  if (k == ~0ull) return;
  int ei = (int)(k & 0xFFFFF);
  int s = src[ei], d = dst[ei];
  if (bcur0[s] == k && bcur0[d] == k) {
    matched[ei] = ~((u32)(k >> 20));
    dead[s] = 1;
    dead[d] = 1;
  }
}

// R9: grid-wide alive-list build (dead stable/read-only here).
__global__ void k_list0(const int* __restrict__ rowptr, const int* __restrict__ gP,
                        const u64* __restrict__ keyA, const u32* __restrict__ sdA,
                        const u8* __restrict__ dead, u64* __restrict__ keyB,
                        u32* __restrict__ sdB, int* __restrict__ gposM, int N) {
  __shared__ int scnt[8], sbase[8];
  if (threadIdx.x < 8) scnt[threadIdx.x] = 0;
  __syncthreads();
  int d = blockIdx.x * blockDim.x + threadIdx.x;
  int g = -1, b = 0, e2 = 0, base = 0, myn = 0, rank = 0;
  if (d < N && !dead[d]) {
    b = rowptr[d]; e2 = rowptr[d + 1];
    if (b < e2) {
      int per = N / *gP;
      g = d / per; base = g * per;
      for (int j = b; j < e2; ++j)
        if (!dead[base + (int)(sdA[j] >> 16)]) ++myn;
      if (myn) rank = atomicAdd(&scnt[g], myn);
    }
  }
  __syncthreads();
  if (threadIdx.x < 8 && scnt[threadIdx.x])
    sbase[threadIdx.x] = atomicAdd(&gposM[threadIdx.x], scnt[threadIdx.x]);
  __syncthreads();
  if (g < 0 || !myn) return;
  int off = rowptr[base] + sbase[g] + rank;
  for (int j = b; j < e2; ++j) {
    if (!dead[base + (int)(sdA[j] >> 16)]) {
      keyB[off] = keyA[j];
      sdB[off] = sdA[j];
      ++off;
    }
  }
}

// Per-graph exact greedy matching from round 1.  (R16 form, measured 161us.)
// Big rounds (n > WAVECAP): global ping-pong with prefetch pipeline.
// n <= WAVECAP -> LDS-resident FULL-BLOCK rounds; nt <= 64 -> DAG solve.
// R19: Phase A global writes skipped when n <= WAVECAP (tail guaranteed).
#define PERMAX 12544
#define WAVECAP 2048
__global__ __launch_bounds__(1024) void k_match_wg(
    const int* __restrict__ rowptr, const int* __restrict__ gP,
    const int* __restrict__ gposM,
    u64* __restrict__ keyB, u64* __restrict__ keyA,
    u32* __restrict__ sdB, u32* __restrict__ sdA,
    u8* __restrict__ dead, u32* __restrict__ matched, int N) {
  __shared__ u64 bcur[PERMAX];
  __shared__ u8 dead_s[PERMAX];
  __shared__ u64 tkey[WAVECAP];
  __shared__ u32 tsd[WAVECAP];
  __shared__ u64 tkey2[WAVECAP];
  __shared__ u32 tsd2[WAVECAP];
  __shared__ int lcnt, lcnt2;
  int G = *gP;
  int g = blockIdx.x;
  if (g >= G) return;
  int per = N / G;
  if (per > PERMAX) per = PERMAX;
  int base = g * per;
  int re = rowptr[base];
  int n = gposM[g];
  int tid = threadIdx.x, lane = tid & 63;
  for (int i = tid; i < per; i += 1024) {
    bcur[i] = ~0ull;
    dead_s[i] = dead[base + i];
  }
  if (tid == 0) lcnt = 0;
  __syncthreads();
  u64* kin = keyB + re; u64* kout = keyA + re;
  u32* sin_ = sdB + re; u32* sout = sdA + re;
  for (int round = 1; n > 0 && round < 4000; ++round) {
    u64 etag = (u64)(4095 - round) << 52;
    bool skipg = (n <= WAVECAP);  // n2 <= n -> tail guaranteed, LDS suffices
    // Phase A: claim minima (fire-and-forget), ballot-compact, prefetched.
    u32 sd_p = 0; u64 k_p = 0;
    if (tid < n) { sd_p = sin_[tid]; k_p = kin[tid]; }
    for (int i = tid; i - lane < n; i += 1024) {
      bool inb = i < n;
      u32 sd = sd_p; u64 k = k_p;
      int inx = i + 1024;
      if (inx < n) { sd_p = sin_[inx]; k_p = kin[inx]; }
      int s = sd >> 16, d = sd & 0xffff;
      bool alive = inb && !(dead_s[s] | dead_s[d]);
      if (alive) {
        u64 val = etag | k;
        atomicMin(&bcur[s], val);
        if (d != s) atomicMin(&bcur[d], val);
      }
      u64 m = __ballot(alive);
      if (m) {
        int lead = __ffsll((long long)m) - 1;
        int bse = 0;
        if (lane == lead) bse = atomicAdd(&lcnt, __popcll(m));
        bse = __shfl(bse, lead, 64);
        if (alive) {
          int j = bse + __popcll(m & ((1ull << lane) - 1ull));
          if (!skipg) {
            kout[j] = k;
            sout[j] = sd;
          }
          if (j < WAVECAP) { tkey[j] = k; tsd[j] = sd; }
        }
      }
    }
    __syncthreads();
    int n2 = lcnt;
    if (n2 == 0) break;
    bool totail = (n2 <= WAVECAP);
    // Phase B: locally-dominant edges match (prefetched on global path)
    u32 sd_q = 0; u64 k_q = 0;
    if (!totail && tid < n2) { sd_q = sout[tid]; k_q = kout[tid]; }
    for (int i = tid; i < n2; i += 1024) {
      u32 sd; u64 k;
      if (totail) { sd = tsd[i]; k = tkey[i]; }
      else {
        sd = sd_q; k = k_q;
        int inx = i + 1024;
        if (inx < n2) { sd_q = sout[inx]; k_q = kout[inx]; }
      }
      int s = sd >> 16, d = sd & 0xffff;
      u64 val = etag | k;
      if (bcur[s] == val && (d == s || bcur[d] == val)) {
        matched[(u32)(k & 0xFFFFF)] = ~((u32)(k >> 20));
        dead_s[s] = 1;
        dead_s[d] = 1;
      }
    }
    if (tid == 0) lcnt = 0;
    __syncthreads();
    if (totail) {
      // ---- R14: LDS-resident full-block rounds (list <= WAVECAP) ----
      int nt = n2;
      int rr = round + 1;
      int cur = 0;
      while (nt > 64 && rr < 4000) {
        u64 et2 = (u64)(4095 - rr) << 52;
        u64* ks = cur ? tkey2 : tkey;
        u32* ss = cur ? tsd2 : tsd;
        u64* kd_ = cur ? tkey : tkey2;
        u32* sd_ = cur ? tsd : tsd2;
        int* cdst = cur ? &lcnt : &lcnt2;
        if (tid == 0) *cdst = 0;
        // claim pass
        for (int i = tid; i < nt; i += 1024) {
          u32 sd = ss[i];
          int s = sd >> 16, d = sd & 0xffff;
          if (dead_s[s] | dead_s[d]) continue;
          u64 val = et2 | ks[i];
          atomicMin(&bcur[s], val);
          if (d != s) atomicMin(&bcur[d], val);
        }
        __syncthreads();  // claims + cdst reset visible
        // fused test + compact into other buffer (order nondeterministic,
        // matching is key-determined -> result exact; dead_s races only
        // add stale entries, filtered by later alive-checks)
        for (int i = tid; i - lane < nt; i += 1024) {
          bool inb = i < nt;
          u32 sd = 0; u64 k = 0;
          if (inb) { sd = ss[i]; k = ks[i]; }
          int s = sd >> 16, d = sd & 0xffff;
          bool alive = false;
          if (inb && !(dead_s[s] | dead_s[d])) {
            u64 val = et2 | k;
            if (bcur[s] == val && (d == s || bcur[d] == val)) {
              matched[(u32)(k & 0xFFFFF)] = ~((u32)(k >> 20));
              dead_s[s] = 1;
              dead_s[d] = 1;
            } else {
              alive = true;
            }
          }
          u64 m = __ballot(alive);
          if (m) {
            int lead = __ffsll((long long)m) - 1;
            int bse = 0;
            if (lane == lead) bse = atomicAdd(cdst, __popcll(m));
            bse = __shfl(bse, lead, 64);
            if (alive) {
              int j = bse + __popcll(m & ((1ull << lane) - 1ull));
              kd_[j] = k;
              sd_[j] = sd;
            }
          }
        }
        __syncthreads();  // deaths + appends complete
        nt = cur ? lcnt : lcnt2;
        cur ^= 1;
        ++rr;
      }
      if (nt > 0) {
        if (tid < 64) {
          // ---- one-shot exact greedy over <=64 edges (single wave) ----
          // list may contain stale-dead entries -> re-check dead_s (list
          // and dead_s are stable here: barrier above).
          u64* ks = cur ? tkey2 : tkey;
          u32* ss = cur ? tsd2 : tsd;
          u64 myk = 0; u32 mysd = 0;
          bool have = lane < nt;
          if (have) { myk = ks[lane]; mysd = ss[lane]; }
          int ms = mysd >> 16, md = mysd & 0xffff;
          if (have && (dead_s[ms] | dead_s[md])) have = false;
          u64 C = 0;
          for (int j = 0; j < nt; ++j) {
            int js = __shfl(ms, j, 64);
            int jd = __shfl(md, j, 64);
            u64 jk = __shfl(myk, j, 64);
            int jh = __shfl((int)have, j, 64);
            bool conf = have && jh && j != lane && jk < myk &&
                        (js == ms || js == md || jd == ms || jd == md);
            if (conf) C |= 1ull << j;
          }
          u64 undec = __ballot(have);
          u64 M = 0;
          while (undec) {
            bool rdy = have && ((undec >> lane) & 1ull) && (C & undec) == 0;
            bool mt = rdy && (C & M) == 0;
            u64 rdym = __ballot(rdy);
            u64 mm = __ballot(mt);
            M |= mm;
            undec &= ~rdym;
            if (!rdym) break;  // safety: DAG guarantees progress
          }
          if (have && ((M >> lane) & 1ull)) {
            matched[(u32)(myk & 0xFFFFF)] = ~((u32)(myk >> 20));
            dead_s[ms] = 1;
            dead_s[md] = 1;
          }
        }
        __syncthreads();
      }
      break;
    }
    u64* tk = kin; kin = kout; kout = tk;
    u32* ts = sin_; sin_ = sout; sout = ts;
    n = n2;
  }
  __syncthreads();
  for (int i = tid; i < per; i += 1024) dead[base + i] = dead_s[i];
}

// R7 two-phase cluster build (512 blocks); also zeroes cnt.
// R16: matched carries score bits -> per-cluster gsc.
__global__ void k_build2(const u32* __restrict__ matched, const int* __restrict__ src,
                         const int* __restrict__ dst, const int* __restrict__ batch,
                         const u8* __restrict__ dead, int* __restrict__ cluster,
                         int* __restrict__ new_batch, int* __restrict__ srcE,
                         float* __restrict__ gsc,
                         int* __restrict__ nclus, float* __restrict__ gccnt,
                         int* __restrict__ cnt, int e, int n, int nc) {
  __shared__ int c_cnt, c_off, basep;
  __shared__ int sc[8];
  if (threadIdx.x == 0) { c_cnt = 0; c_off = 0; basep = 0; }
  if (threadIdx.x < 8) sc[threadIdx.x] = 0;
  __syncthreads();
  int nbk = gridDim.x;
  for (int i = blockIdx.x * blockDim.x + threadIdx.x; i < nc; i += nbk * blockDim.x) cnt[i] = 0;
  int ec = (e + nbk - 1) / nbk, es = blockIdx.x * ec, ee = es + ec; if (ee > e) ee = e;
  int nk = (n + nbk - 1) / nbk, ns = blockIdx.x * nk, ne = ns + nk; if (ne > n) ne = n;
  int my = 0;
  for (int i = es + threadIdx.x; i < ee; i += blockDim.x) if (matched[i]) ++my;
  for (int i = ns + threadIdx.x; i < ne; i += blockDim.x) if (!dead[i]) ++my;
  if (my) atomicAdd(&c_cnt, my);
  __syncthreads();
  if (threadIdx.x == 0 && c_cnt) basep = atomicAdd(nclus, c_cnt);
  __syncthreads();
  int bse = basep;
  for (int i = es + threadIdx.x; i < ee; i += blockDim.x) {
    u32 m = matched[i];
    if (!m) continue;
    int c = bse + atomicAdd(&c_off, 1);
    int s = src[i], d = dst[i];
    cluster[s] = c;
    cluster[d] = c;
    srcE[c] = i;
    gsc[c] = __uint_as_float(m);
    int g = batch[s];
    new_batch[c] = g;
    if ((unsigned)g < 8u) atomicAdd(&sc[g], 1);
  }
  for (int i = ns + threadIdx.x; i < ne; i += blockDim.x) {
    if (dead[i]) continue;
    int c = bse + atomicAdd(&c_off, 1);
    cluster[i] = c;
    srcE[c] = ~i;  // singleton: encoded node
    gsc[c] = 1.0f;
    int g = batch[i];
    new_batch[c] = g;
    if ((unsigned)g < 8u) atomicAdd(&sc[g], 1);
  }
  __syncthreads();
  if (threadIdx.x < 8 && sc[threadIdx.x] > 0)
    atomicAdd(&gccnt[threadIdx.x], (float)sc[threadIdx.x]);
}

#define HBITS 21
#define HMASK ((1u << HBITS) - 1u)

// cluster-driven new_x (wave per cluster) + hash-table init prologue.
// R16: score via per-cluster gsc (coalesced) instead of random score[eid].
__global__ void k_newx(const int* __restrict__ srcE, const int* __restrict__ src,
                       const int* __restrict__ dst, const float* __restrict__ gsc,
                       const int* __restrict__ nclusP, const float* __restrict__ h2,
                       float* __restrict__ new_x, u64* __restrict__ table, int n) {
  int idx = blockIdx.x * blockDim.x + threadIdx.x;
  if (idx < (1 << HBITS)) table[idx] = ~0ull;
  int c = idx >> 6;
  int lane = idx & 63;
  if (c >= n || c >= *nclusP) return;
  int v = srcE[c];
  float val;
  if (v >= 0) {
    int s = src[v], d = dst[v];
    val = h2[(size_t)s * 64 + lane];
    if (d != s) val += h2[(size_t)d * 64 + lane];
    val *= gsc[c];
  } else {
    val = h2[(size_t)(~v) * 64 + lane];
  }
  new_x[(size_t)c * 64 + lane] = val;
}

// coalesce(cluster[edge_index]): hash-dedup; dups -> sentinel n; counts kept.
__global__ void k_dedup(const int* __restrict__ src, const int* __restrict__ dst,
                        const int* __restrict__ cluster, u64* __restrict__ table,
                        int* __restrict__ ns, int* __restrict__ nd,
                        int* __restrict__ cnt, int e, int n) {
  int i = blockIdx.x * blockDim.x + threadIdx.x;
  if (i >= e) return;
  int cs_ = cluster[src[i]], cd_ = cluster[dst[i]];
  u64 kk = (u64)cs_ * (u64)(n + 1) + (u64)cd_;
  u32 pos = (u32)((kk * 0x9E3779B97F4A7C15ull) >> 43) & HMASK;
  while (true) {
    u64 old = atomicCAS(&table[pos], ~0ull, kk);
    if (old == ~0ull) {
      ns[i] = cs_; nd[i] = cd_;
      atomicAdd(&cnt[cd_], 1);
      return;
    }
    if (old == kk) { ns[i] = n; nd[i] = n; return; }
    pos = (pos + 1) & HMASK;
  }
}

// JK cat (partial-buffer reduce) + lin1 + relu + lin2 + log_softmax.
// R16: one block per graph (was 1 block total).  FP order identical.
__global__ void k_head(const float* __restrict__ xs_part /*[4][64][512]*/,
                       const float* __restrict__ gn_part /*[64][8]*/,
                       const float* __restrict__ gccnt,
                       const float* __restrict__ l1w, const float* __restrict__ l1b,
                       const float* __restrict__ l2w, const float* __restrict__ l2b,
                       const int* __restrict__ gP, float* __restrict__ out, int C) {
  __shared__ float z[256];
  __shared__ float z1[64];
  __shared__ float z2[16];
  __shared__ float gnc;
  int G = *gP;
  int g = blockIdx.x;
  if (g >= G) return;
  int tid = threadIdx.x;
  if (tid < 64) {
    float s = gn_part[tid * 8 + g];
#pragma unroll
    for (int off = 32; off > 0; off >>= 1) s += __shfl_down(s, off, 64);
    if (tid == 0) gnc = s;
  }
  __syncthreads();
  {
    int p = tid >> 6, f = tid & 63;
    const float* xp = xs_part + (size_t)p * 64 * 512;
    float s = 0.f;
    for (int b = 0; b < 64; ++b) s += xp[b * 512 + g * 64 + f];
    float c = (p < 2) ? gnc : gccnt[g];
    if (c < 1.f) c = 1.f;
    z[tid] = s / c;
  }
  __syncthreads();
  if (tid < 64) {
    int o = tid;
    float a = l1b[o];
    for (int k = 0; k < 256; ++k) a = fmaf(z[k], l1w[o * 256 + k], a);
    z1[o] = a > 0.f ? a : 0.f;
  }
  __syncthreads();
  if (tid < C) {
    int c = tid;
    float a = l2b[c];
    for (int k = 0; k < 64; ++k) a = fmaf(z1[k], l2w[c * 64 + k], a);
    z2[c] = a;
  }
  __syncthreads();
  if (tid == 0) {
    float m = z2[0];
    for (int c = 1; c < C; ++c) m = fmaxf(m, z2[c]);
    float s = 0.f;
    for (int c = 0; c < C; ++c) s += expf(z2[c] - m);
    float lse = m + logf(s);
    for (int c = 0; c < C; ++c) out[g * C + c] = z2[c] - lse;
  }
}

extern "C" void kernel_launch(void* const* d_in, const int* in_sizes, int n_in,
                              void* d_out, int out_size, void* d_ws, size_t ws_size,
                              hipStream_t stream) {
  const float* x       = (const float*)d_in[0];
  const int*   ei      = (const int*)d_in[1];
  const int*   batch   = (const int*)d_in[2];
  const float* w_rel1  = (const float*)d_in[3];
  const float* b_rel1  = (const float*)d_in[4];
  const float* w_root1 = (const float*)d_in[5];
  const float* w_rel2  = (const float*)d_in[6];
  const float* b_rel2  = (const float*)d_in[7];
  const float* w_root2 = (const float*)d_in[8];
  const float* w_rel3  = (const float*)d_in[9];
  const float* b_rel3  = (const float*)d_in[10];
  const float* w_root3 = (const float*)d_in[11];
  const float* w_rel4  = (const float*)d_in[12];
  const float* b_rel4  = (const float*)d_in[13];
  const float* w_root4 = (const float*)d_in[14];
  const float* pool_w  = (const float*)d_in[15];
  const float* pool_b  = (const float*)d_in[16];
  const float* lin1_w  = (const float*)d_in[17];
  const float* lin1_b  = (const float*)d_in[18];
  const float* lin2_w  = (const float*)d_in[19];
  const float* lin2_b  = (const float*)d_in[20];
  const int*   gP      = (const int*)d_in[21];
  float* out = (float*)d_out;

  const int N = in_sizes[2];
  const int E = in_sizes[1] / 2;
  const int C = in_sizes[20];
  const int* src = ei;
  const int* dst = ei + E;

  // ---- workspace layout ----
  char* w = (char*)d_ws;
  auto alloc = [&](size_t bytes) -> char* {
    char* p = w;
    w += (bytes + 255) & ~(size_t)255;
    return p;
  };
  float* r      = (float*)alloc((size_t)N * 64 * 4);
  float* agg    = (float*)alloc((size_t)(N + 1) * 64 * 4);  // u / match lists / hash
  float* hA     = (float*)alloc((size_t)N * 64 * 4);        // h1 -> new_x -> h4
  float* hB     = (float*)alloc((size_t)N * 64 * 4);        // h2 -> h3
  float* gsc    = (float*)alloc((size_t)(N + 2) * 4);       // per-cluster score
  int*   colbuf = (int*)alloc((size_t)E * 8);               // col + eid
  int*   listA  = (int*)alloc((size_t)E * 4);               // aN -> ns
  int*   listB  = (int*)alloc((size_t)E * 4);               // bN -> nd
  int*   rowptr = (int*)alloc((size_t)(N + 2) * 4);
  int*   pos    = (int*)alloc((size_t)(N + 2) * 4);         // also srcE
  char* zstart = w;                                         // zeroed block
  int*   cnt       = (int*)alloc((size_t)(N + 2) * 4);
  int*   bsum      = (int*)alloc(1024);
  u8*    dead      = (u8*)alloc((size_t)N);
  u32*   matched   = (u32*)alloc((size_t)E * 4);            // score bits or 0
  int*   cluster   = (int*)alloc((size_t)N * 4);
  int*   new_batch = (int*)alloc((size_t)N * 4);
  float* xs_part   = (float*)alloc((size_t)4 * 64 * 512 * 4);  // per-stage partials
  float* gn_part   = (float*)alloc((size_t)64 * 8 * 4);
  float* small     = (float*)alloc(16384);
  size_t zbytes = (size_t)(w - zstart);
  if ((size_t)(w - (char*)d_ws) > ws_size) return;  // fail loudly

  int*   col = colbuf;         // CSR src per slot
  int*   eid = colbuf + E;     // CSR original-edge id per slot
  float* aN  = (float*)listA;  // alias: dots dead before ns/nd used
  float* bN  = (float*)listB;
  float* uB  = agg;            // u for all convs (agg phase-disjoint)
  u64*   keyA = (u64*)agg;     // score/key output + match ping-pong
  u64*   keyB = keyA + E;
  u32*   sdA  = (u32*)(keyB + E);
  u32*   sdB  = sdA + E;
  u64*   bcur0 = (u64*)(sdB + E);  // round-0 global minima (tail of agg)
  u64*   table = (u64*)agg;    // hash (after match, before conv3)
  int*   srcE = pos;           // alias: pos re-filled later by 2nd scan_out

  float* gccnt  = small;                 // [8]
  int*   nclusP = (int*)(small + 16);
  int*   gposM  = (int*)(small + 32);    // [8] alive-list counters (zeroed)

  const int TB = 256;
  const int chunks = (((N + 511) / 512) + 7) & ~7;  // %8==0 for XCD grouping
  const int gT = chunks * 4;                        // x: {xcd, oq, chunk}
  const int gN = (N + TB - 1) / TB;
  const int gE = (E + TB - 1) / TB;
  const int gE1k = (E + 1023) >> 10;
  const int gNw = (int)(((size_t)N * 64 + TB - 1) / TB);  // wave per node
  const int swz = (gNw % 8 == 0) ? 1 : 0;
  const int nc = N + 2;
  const int nb = (nc + 1023) / 1024;

  hipMemsetAsync(zstart, 0, zbytes, stream);

  // ---- CSR for original edges ----
  k_count<<<gE1k, TB, 0, stream>>>(dst, cnt, E);
  k_scan_sums<<<nb, TB, 0, stream>>>(cnt, bsum, nc);
  k_scan_out<<<nb, TB, 0, stream>>>(cnt, bsum, rowptr, pos, nc, nb);
  k_fill<<<gE, TB, 0, stream>>>(src, dst, pos, col, eid, bcur0, N, E, N);

  // ---- conv1 (F=128 -> 64) ----
  k_transform2<128><<<gT, TB, 0, stream>>>(x, w_rel1, w_root1, b_rel1, nullptr, r, uB, N);
  k_gfin2<<<gNw, TB, 0, stream>>>(r, uB, rowptr, col, batch, gP, nullptr, hA,
                                  nullptr, nullptr, nullptr, xs_part + 0 * 32768, gn_part, N, swz);

  // ---- conv2 (64 -> 64, + score dots) ----
  k_transform2<64><<<gT, TB, 0, stream>>>(hA, w_rel2, w_root2, b_rel2, nullptr, r, uB, N);
  k_gfin2<<<gNw, TB, 0, stream>>>(r, uB, rowptr, col, batch, gP, nullptr, hB,
                                  pool_w, aN, bN, xs_part + 1 * 32768, nullptr, N, swz);

  // ---- scoring (CSR order) + grid-wide matching round 0 ----
  k_score_csr<<<gN, TB, 0, stream>>>(aN, bN, pool_b, rowptr, col, eid, gP,
                                     keyA, sdA, bcur0, N);
  k_match0<<<gN, TB, 0, stream>>>(src, dst, bcur0, matched, dead, N);
  k_list0<<<gN, TB, 0, stream>>>(rowptr, gP, keyA, sdA, dead, keyB, sdB, gposM, N);

  // ---- greedy matching rounds 1+ (per-graph WG, LDS state, LDS tail) ----
  k_match_wg<<<8, 1024, 0, stream>>>(rowptr, gP, gposM, keyB, keyA, sdB, sdA,
                                     dead, matched, N);

  // ---- clusters (two-phase), new_x (+hash init), dedup + pooled CSR ----
  k_build2<<<512, TB, 0, stream>>>(matched, src, dst, batch, dead, cluster, new_batch,
                                   srcE, gsc, nclusP, gccnt, cnt, E, N, nc);
  k_newx<<<gNw, TB, 0, stream>>>(srcE, src, dst, gsc, nclusP, hB, hA, table, N);
  k_dedup<<<gE, TB, 0, stream>>>(src, dst, cluster, table, listA, listB, cnt, E, N);
  k_scan_sums<<<nb, TB, 0, stream>>>(cnt, bsum, nc);
  k_scan_out<<<nb, TB, 0, stream>>>(cnt, bsum, rowptr, pos, nc, nb);
  k_fill<<<gE, TB, 0, stream>>>(listA, listB, pos, col, nullptr, nullptr, 0, E, N);

  // ---- conv3 (64 -> 64, pooled) ----
  k_transform2<64><<<gT, TB, 0, stream>>>(hA, w_rel3, w_root3, b_rel3, nclusP, r, uB, N);
  k_gfin2<<<gNw, TB, 0, stream>>>(r, uB, rowptr, col, new_batch, gP, nclusP, hB,
                                  nullptr, nullptr, nullptr, xs_part + 2 * 32768, nullptr, N, 0);

  // ---- conv4 (64 -> 64, pooled) ----
  k_transform2<64><<<gT, TB, 0, stream>>>(hB, w_rel4, w_root4, b_rel4, nclusP, r, uB, N);
  k_gfin2<<<gNw, TB, 0, stream>>>(r, uB, rowptr, col, new_batch, gP, nclusP, hA,
                                  nullptr, nullptr, nullptr, xs_part + 3 * 32768, nullptr, N, 0);

  // ---- head ----
  k_head<<<8, TB, 0, stream>>>(xs_part, gn_part, gccnt, lin1_w, lin1_b, lin2_w, lin2_b, gP, out, C);
}

// Round 13
// 1070.848 us; speedup vs baseline: 1.0560x; 1.0068x over previous
//
#include <hip/hip_runtime.h>
#include <stdint.h>

typedef unsigned long long u64;
typedef unsigned int u32;
typedef unsigned char u8;

// ---------------------------------------------------------------------------
// EdgePool GNN pipeline.  N=100000, E=800000, F=128, H=64, G=8, C=10. f32.
// R1 two-stage gmp · R2 dst-CSR gather · R4 match state in LDS · R5 XCD
// swizzle + epoch bcur + no-max softmax · R7 wave-per-node gfin2 + partial
// gmp flush + two-phase build · R8 CSR-ordered scoring · R9 grid-wide
// matching round 0 · R14 LDS-resident match mid-tail · R16 prefetch +
// score-in-key + per-graph head · R18 gfin2 unroll · R19 O(N) match0 ·
// R20 2-node o-quarter transform + gfin2 x8 + u8 dead · R22 two-kernel
// scan restored + bcur0-fold kept.
// R23: newx + dedup are mutually independent once the hash-table init
//      moves into build2 (both consume only build2 outputs). Merged into
//      one kernel k_nd: cluster-driven new_x gather and edge-driven
//      hash-CAS dedup run concurrently in one dispatch (saves a launch +
//      overlaps two memory-bound phases). table aliases agg whose last
//      reader is match_wg; build2 runs after -> safe.
// ---------------------------------------------------------------------------

// 1D grid = chunks*4, chunks % 8 == 0.  bid -> {xcd=bid&7, oq=(bid>>3)&3,
// chunk=(bid>>5)*8+xcd}: a chunk's 4 o-quarter blocks share an XCD.
template <int K>
__global__ __launch_bounds__(256) void k_transform2(
    const float* __restrict__ x, const float* __restrict__ wrel,
    const float* __restrict__ wroot, const float* __restrict__ bias,
    const int* __restrict__ nvP, float* __restrict__ r,
    float* __restrict__ u, int n) {
  __shared__ float wsR[16 * K];
  __shared__ float wsU[16 * K];
  int xcd = blockIdx.x & 7;
  int s = blockIdx.x >> 3;
  int oq = s & 3;
  int chunk = (s >> 2) * 8 + xcd;
  const int ob = oq * 16;
  const float* __restrict__ wA = wrel + (size_t)ob * K;
  const float* __restrict__ wB = wroot + (size_t)ob * K;
  for (int i = threadIdx.x; i < 4 * K; i += 256) {
    reinterpret_cast<float4*>(wsR)[i] = reinterpret_cast<const float4*>(wA)[i];
    reinterpret_cast<float4*>(wsU)[i] = reinterpret_cast<const float4*>(wB)[i];
  }
  int nv = n;
  if (nvP) { int v = *nvP; if (v < nv) nv = v; }
  int node0 = chunk * 512 + threadIdx.x;
  int node1 = node0 + 256;
  bool act0 = node0 < nv;
  bool act1 = node1 < nv;
  __syncthreads();
  if (!(act0 | act1)) return;
  // clamp inactive rows to row 0: harmless reads, writes guarded below
  const float* xr0 = x + (size_t)(act0 ? node0 : 0) * K;
  const float* xr1 = x + (size_t)(act1 ? node1 : 0) * K;
  float aR0[16], aU0[16], aR1[16], aU1[16];
#pragma unroll
  for (int o = 0; o < 16; ++o) {
    float b = bias[ob + o];
    aR0[o] = 0.f; aR1[o] = 0.f;
    aU0[o] = b;   aU1[o] = b;
  }
  for (int k = 0; k < K; k += 4) {
    float4 xv0 = *reinterpret_cast<const float4*>(xr0 + k);
    float4 xv1 = *reinterpret_cast<const float4*>(xr1 + k);
#pragma unroll
    for (int o = 0; o < 16; ++o) {
      float4 wv = *reinterpret_cast<const float4*>(&wsR[o * K + k]);
      aR0[o] = fmaf(xv0.x, wv.x, aR0[o]);
      aR0[o] = fmaf(xv0.y, wv.y, aR0[o]);
      aR0[o] = fmaf(xv0.z, wv.z, aR0[o]);
      aR0[o] = fmaf(xv0.w, wv.w, aR0[o]);
      aR1[o] = fmaf(xv1.x, wv.x, aR1[o]);
      aR1[o] = fmaf(xv1.y, wv.y, aR1[o]);
      aR1[o] = fmaf(xv1.z, wv.z, aR1[o]);
      aR1[o] = fmaf(xv1.w, wv.w, aR1[o]);
      float4 wu = *reinterpret_cast<const float4*>(&wsU[o * K + k]);
      aU0[o] = fmaf(xv0.x, wu.x, aU0[o]);
      aU0[o] = fmaf(xv0.y, wu.y, aU0[o]);
      aU0[o] = fmaf(xv0.z, wu.z, aU0[o]);
      aU0[o] = fmaf(xv0.w, wu.w, aU0[o]);
      aU1[o] = fmaf(xv1.x, wu.x, aU1[o]);
      aU1[o] = fmaf(xv1.y, wu.y, aU1[o]);
      aU1[o] = fmaf(xv1.z, wu.z, aU1[o]);
      aU1[o] = fmaf(xv1.w, wu.w, aU1[o]);
    }
  }
  if (act0) {
    float4* op = reinterpret_cast<float4*>(r + (size_t)node0 * 64 + ob);
#pragma unroll
    for (int o = 0; o < 4; ++o)
      op[o] = make_float4(aR0[4 * o], aR0[4 * o + 1], aR0[4 * o + 2], aR0[4 * o + 3]);
    op = reinterpret_cast<float4*>(u + (size_t)node0 * 64 + ob);
#pragma unroll
    for (int o = 0; o < 4; ++o)
      op[o] = make_float4(aU0[4 * o], aU0[4 * o + 1], aU0[4 * o + 2], aU0[4 * o + 3]);
  }
  if (act1) {
    float4* op = reinterpret_cast<float4*>(r + (size_t)node1 * 64 + ob);
#pragma unroll
    for (int o = 0; o < 4; ++o)
      op[o] = make_float4(aR1[4 * o], aR1[4 * o + 1], aR1[4 * o + 2], aR1[4 * o + 3]);
    op = reinterpret_cast<float4*>(u + (size_t)node1 * 64 + ob);
#pragma unroll
    for (int o = 0; o < 4; ++o)
      op[o] = make_float4(aU1[4 * o], aU1[4 * o + 1], aU1[4 * o + 2], aU1[4 * o + 3]);
  }
}

// dst-degree count; 1024-edge chunks
__global__ void k_count(const int* __restrict__ dst, int* __restrict__ cnt, int e) {
  int base = blockIdx.x << 10;
#pragma unroll
  for (int k = 0; k < 4; ++k) {
    int i = base + k * 256 + threadIdx.x;
    if (i < e) atomicAdd(&cnt[dst[i]], 1);
  }
}

// ---- scan over nc ints (2 kernels; scan_out folds the block-sum prefix) ----
__global__ void k_scan_sums(const int* __restrict__ in, int* __restrict__ bsum, int n) {
  __shared__ int sd[256];
  int base = blockIdx.x << 10;
  int s = 0;
  for (int j = threadIdx.x; j < 1024; j += 256) {
    int id = base + j;
    s += (id < n) ? in[id] : 0;
  }
  sd[threadIdx.x] = s;
  __syncthreads();
  for (int w = 128; w > 0; w >>= 1) {
    if (threadIdx.x < w) sd[threadIdx.x] += sd[threadIdx.x + w];
    __syncthreads();
  }
  if (threadIdx.x == 0) bsum[blockIdx.x] = sd[0];
}
__global__ void k_scan_out(const int* __restrict__ in, const int* __restrict__ bsum,
                           int* __restrict__ rowptr, int* __restrict__ pos, int n, int nb) {
  __shared__ int sd[256];
  __shared__ int sb[256];
  for (int i = threadIdx.x; i < 256; i += 256) sb[i] = (i < nb) ? bsum[i] : 0;
  int base = blockIdx.x << 10;
  int i0 = base + threadIdx.x * 4;
  int v0 = 0, v1 = 0, v2 = 0, v3 = 0;
  if (i0 < n) v0 = in[i0];
  if (i0 + 1 < n) v1 = in[i0 + 1];
  if (i0 + 2 < n) v2 = in[i0 + 2];
  if (i0 + 3 < n) v3 = in[i0 + 3];
  sd[threadIdx.x] = v0 + v1 + v2 + v3;
  __syncthreads();
  for (int off = 1; off < 256; off <<= 1) {
    int add = (threadIdx.x >= off) ? sd[threadIdx.x - off] : 0;
    __syncthreads();
    sd[threadIdx.x] += add;
    __syncthreads();
  }
  int basev = 0;
  for (int b2 = 0; b2 < blockIdx.x; ++b2) basev += sb[b2];
  int excl = basev + (threadIdx.x ? sd[threadIdx.x - 1] : 0);
  if (i0 < n) { rowptr[i0] = excl; pos[i0] = excl; }
  excl += v0;
  if (i0 + 1 < n) { rowptr[i0 + 1] = excl; pos[i0 + 1] = excl; }
  excl += v1;
  if (i0 + 2 < n) { rowptr[i0 + 2] = excl; pos[i0 + 2] = excl; }
  excl += v2;
  if (i0 + 3 < n) { rowptr[i0 + 3] = excl; pos[i0 + 3] = excl; }
}

// CSR fill: col = src, eid = original edge index.
// R21: optionally ~0-inits bcur0 (folds a memset launch; i<nb0 threads).
__global__ void k_fill(const int* __restrict__ src, const int* __restrict__ dst,
                       int* __restrict__ pos, int* __restrict__ col,
                       int* __restrict__ eid, u64* __restrict__ bc0, int nb0,
                       int e, int n) {
  int i = blockIdx.x * blockDim.x + threadIdx.x;
  if (i >= e) return;
  if (bc0 && i < nb0) bc0[i] = ~0ull;
  int d = dst[i];
  if (d >= n) return;  // sentinel (pooled duplicates)
  int j = atomicAdd(&pos[d], 1);
  col[j] = src[i];
  if (eid) eid[j] = i;
}

// R7 fused conv tail: wave-per-node gather + mean + relu + h-write (+dots),
// gmp accumulated in LDS, flushed to 64 partial buffers (presence-masked).
// R20: gather unrolled x8 (scalar col loads batched ahead of vector loads;
// FP accumulation order unchanged, index-ascending).
__global__ void k_gfin2(const float* __restrict__ r, const float* __restrict__ u,
                        const int* __restrict__ rowptr, const int* __restrict__ col,
                        const int* __restrict__ batch, const int* __restrict__ gP,
                        const int* __restrict__ nvP, float* __restrict__ h,
                        const float* __restrict__ pw, float* __restrict__ aN,
                        float* __restrict__ bN, float* __restrict__ xs_part /*[64][512]*/,
                        float* __restrict__ gn_part /*[64][8] or null*/, int n, int swz) {
  __shared__ float sacc[512];
  __shared__ float scnt8[8];
  __shared__ float pws[128];
  __shared__ int pres;
  int G = *gP;
  int nv = nvP ? *nvP : n;
  if (nv > n) nv = n;
  for (int i = threadIdx.x; i < 512; i += 256) sacc[i] = 0.f;
  if (threadIdx.x < 8) scnt8[threadIdx.x] = 0.f;
  if (threadIdx.x == 0) pres = 0;
  if (pw && threadIdx.x < 128) pws[threadIdx.x] = pw[threadIdx.x];
  __syncthreads();
  int b = blockIdx.x;
  if (swz) { int chunk = gridDim.x >> 3; b = (b & 7) * chunk + (b >> 3); }
  int lane = threadIdx.x & 63, w = threadIdx.x >> 6;
  int node = b * 4 + w;
  if (node < nv) {
    int bg = rowptr[node], e2 = rowptr[node + 1];
    float s = 0.f;
    int j = bg;
    for (; j + 8 <= e2; j += 8) {
      int c0 = col[j], c1 = col[j + 1], c2 = col[j + 2], c3 = col[j + 3];
      int c4 = col[j + 4], c5 = col[j + 5], c6 = col[j + 6], c7 = col[j + 7];
      float v0 = r[(size_t)c0 * 64 + lane];
      float v1 = r[(size_t)c1 * 64 + lane];
      float v2 = r[(size_t)c2 * 64 + lane];
      float v3 = r[(size_t)c3 * 64 + lane];
      float v4 = r[(size_t)c4 * 64 + lane];
      float v5 = r[(size_t)c5 * 64 + lane];
      float v6 = r[(size_t)c6 * 64 + lane];
      float v7 = r[(size_t)c7 * 64 + lane];
      s += v0; s += v1; s += v2; s += v3;
      s += v4; s += v5; s += v6; s += v7;
    }
    for (; j + 4 <= e2; j += 4) {
      int c0 = col[j], c1 = col[j + 1], c2 = col[j + 2], c3 = col[j + 3];
      float v0 = r[(size_t)c0 * 64 + lane];
      float v1 = r[(size_t)c1 * 64 + lane];
      float v2 = r[(size_t)c2 * 64 + lane];
      float v3 = r[(size_t)c3 * 64 + lane];
      s += v0; s += v1; s += v2; s += v3;
    }
    for (; j < e2; ++j) s += r[(size_t)col[j] * 64 + lane];
    int deg = e2 - bg;
    float inv = deg > 0 ? 1.f / (float)deg : 0.f;
    float v = fmaf(s, inv, u[(size_t)node * 64 + lane]);
    v = v > 0.f ? v : 0.f;
    h[(size_t)node * 64 + lane] = v;
    if (pw) {
      float d1 = v * pws[lane];
      float d2 = v * pws[64 + lane];
#pragma unroll
      for (int off = 32; off > 0; off >>= 1) {
        d1 += __shfl_down(d1, off, 64);
        d2 += __shfl_down(d2, off, 64);
      }
      if (lane == 0) { aN[node] = d1; bN[node] = d2; }
    }
    int g = batch[node];
    if ((unsigned)g < 8u && g < G) {
      atomicAdd(&sacc[g * 64 + lane], v);
      if (lane == 0) {
        atomicOr(&pres, 1 << g);
        if (gn_part) atomicAdd(&scnt8[g], 1.f);
      }
    }
  }
  __syncthreads();
  int pm = pres;
  if (!pm) return;
  int buf = blockIdx.x & 63;
  float* xp = xs_part + buf * 512;
  for (int i = threadIdx.x; i < 512; i += 256) {
    if ((pm >> (i >> 6)) & 1) {
      float s2 = sacc[i];
      if (s2 != 0.f) atomicAdd(&xp[i], s2);
    }
  }
  if (gn_part && threadIdx.x < 8) {
    float c = scnt8[threadIdx.x];
    if (c != 0.f) atomicAdd(&gn_part[buf * 8 + threadIdx.x], c);
  }
}

// R8/R9: CSR-ordered scoring + round-0 priority claim into global bcur0.
// R15: pass-1 expf cached in sdA[j].  R16: no score[] scatter (score bits
// travel in the key; recovered at match time).
__global__ void k_score_csr(const float* __restrict__ aN, const float* __restrict__ bN,
                            const float* __restrict__ pbp, const int* __restrict__ rowptr,
                            const int* __restrict__ col, const int* __restrict__ eid,
                            const int* __restrict__ gP,
                            u64* __restrict__ keyA, u32* __restrict__ sdA,
                            u64* __restrict__ bcur0, int N) {
  int d = blockIdx.x * blockDim.x + threadIdx.x;
  if (d >= N) return;
  int b = rowptr[d], e2 = rowptr[d + 1];
  if (b == e2) return;
  float bd = bN[d] + pbp[0];
  float den = 0.f;
  for (int j = b; j < e2; ++j) {
    float ex = expf(aN[col[j]] + bd);
    sdA[j] = __float_as_uint(ex);  // cache; overwritten in pass 2
    den += ex;
  }
  int per = N / *gP;
  int g = d / per;
  int base = g * per;
  u32 dl = (u32)(d - base);
  u64 rmin = ~0ull;
  for (int j = b; j < e2; ++j) {
    int s = col[j];
    int ei = eid[j];
    float ex = __uint_as_float(sdA[j]);
    float sc = ex / den + 0.5f;
    u64 k = ((u64)(u32)(~__float_as_uint(sc)) << 20) | (u32)ei;
    keyA[j] = k;
    sdA[j] = ((u32)(s - base) << 16) | dl;
    atomicMin(&bcur0[s], k);
    if (k < rmin) rmin = k;
  }
  atomicMin(&bcur0[d], rmin);
}

// R19: O(N) round-0 match test.  An edge matches iff it is the min key at
// both endpoints; the only candidate at node v is bcur0[v] itself, whose
// endpoints come from src/dst[eid].  bcur0 read-only -> deterministic.
__global__ void k_match0(const int* __restrict__ src, const int* __restrict__ dst,
                         const u64* __restrict__ bcur0, u32* __restrict__ matched,
                         u8* __restrict__ dead, int N) {
  int v = blockIdx.x * blockDim.x + threadIdx.x;
  if (v >= N) return;
  u64 k = bcur0[v];
  if (k == ~0ull) return;
  int ei = (int)(k & 0xFFFFF);
  int s = src[ei], d = dst[ei];
  if (bcur0[s] == k && bcur0[d] == k) {
    matched[ei] = ~((u32)(k >> 20));
    dead[s] = 1;
    dead[d] = 1;
  }
}

// R9: grid-wide alive-list build (dead stable/read-only here).
__global__ void k_list0(const int* __restrict__ rowptr, const int* __restrict__ gP,
                        const u64* __restrict__ keyA, const u32* __restrict__ sdA,
                        const u8* __restrict__ dead, u64* __restrict__ keyB,
                        u32* __restrict__ sdB, int* __restrict__ gposM, int N) {
  __shared__ int scnt[8], sbase[8];
  if (threadIdx.x < 8) scnt[threadIdx.x] = 0;
  __syncthreads();
  int d = blockIdx.x * blockDim.x + threadIdx.x;
  int g = -1, b = 0, e2 = 0, base = 0, myn = 0, rank = 0;
  if (d < N && !dead[d]) {
    b = rowptr[d]; e2 = rowptr[d + 1];
    if (b < e2) {
      int per = N / *gP;
      g = d / per; base = g * per;
      for (int j = b; j < e2; ++j)
        if (!dead[base + (int)(sdA[j] >> 16)]) ++myn;
      if (myn) rank = atomicAdd(&scnt[g], myn);
    }
  }
  __syncthreads();
  if (threadIdx.x < 8 && scnt[threadIdx.x])
    sbase[threadIdx.x] = atomicAdd(&gposM[threadIdx.x], scnt[threadIdx.x]);
  __syncthreads();
  if (g < 0 || !myn) return;
  int off = rowptr[base] + sbase[g] + rank;
  for (int j = b; j < e2; ++j) {
    if (!dead[base + (int)(sdA[j] >> 16)]) {
      keyB[off] = keyA[j];
      sdB[off] = sdA[j];
      ++off;
    }
  }
}

// Per-graph exact greedy matching from round 1.  (R16 form, measured 161us.)
// Big rounds (n > WAVECAP): global ping-pong with prefetch pipeline.
// n <= WAVECAP -> LDS-resident FULL-BLOCK rounds; nt <= 64 -> DAG solve.
// R19: Phase A global writes skipped when n <= WAVECAP (tail guaranteed).
#define PERMAX 12544
#define WAVECAP 2048
__global__ __launch_bounds__(1024) void k_match_wg(
    const int* __restrict__ rowptr, const int* __restrict__ gP,
    const int* __restrict__ gposM,
    u64* __restrict__ keyB, u64* __restrict__ keyA,
    u32* __restrict__ sdB, u32* __restrict__ sdA,
    u8* __restrict__ dead, u32* __restrict__ matched, int N) {
  __shared__ u64 bcur[PERMAX];
  __shared__ u8 dead_s[PERMAX];
  __shared__ u64 tkey[WAVECAP];
  __shared__ u32 tsd[WAVECAP];
  __shared__ u64 tkey2[WAVECAP];
  __shared__ u32 tsd2[WAVECAP];
  __shared__ int lcnt, lcnt2;
  int G = *gP;
  int g = blockIdx.x;
  if (g >= G) return;
  int per = N / G;
  if (per > PERMAX) per = PERMAX;
  int base = g * per;
  int re = rowptr[base];
  int n = gposM[g];
  int tid = threadIdx.x, lane = tid & 63;
  for (int i = tid; i < per; i += 1024) {
    bcur[i] = ~0ull;
    dead_s[i] = dead[base + i];
  }
  if (tid == 0) lcnt = 0;
  __syncthreads();
  u64* kin = keyB + re; u64* kout = keyA + re;
  u32* sin_ = sdB + re; u32* sout = sdA + re;
  for (int round = 1; n > 0 && round < 4000; ++round) {
    u64 etag = (u64)(4095 - round) << 52;
    bool skipg = (n <= WAVECAP);  // n2 <= n -> tail guaranteed, LDS suffices
    // Phase A: claim minima (fire-and-forget), ballot-compact, prefetched.
    u32 sd_p = 0; u64 k_p = 0;
    if (tid < n) { sd_p = sin_[tid]; k_p = kin[tid]; }
    for (int i = tid; i - lane < n; i += 1024) {
      bool inb = i < n;
      u32 sd = sd_p; u64 k = k_p;
      int inx = i + 1024;
      if (inx < n) { sd_p = sin_[inx]; k_p = kin[inx]; }
      int s = sd >> 16, d = sd & 0xffff;
      bool alive = inb && !(dead_s[s] | dead_s[d]);
      if (alive) {
        u64 val = etag | k;
        atomicMin(&bcur[s], val);
        if (d != s) atomicMin(&bcur[d], val);
      }
      u64 m = __ballot(alive);
      if (m) {
        int lead = __ffsll((long long)m) - 1;
        int bse = 0;
        if (lane == lead) bse = atomicAdd(&lcnt, __popcll(m));
        bse = __shfl(bse, lead, 64);
        if (alive) {
          int j = bse + __popcll(m & ((1ull << lane) - 1ull));
          if (!skipg) {
            kout[j] = k;
            sout[j] = sd;
          }
          if (j < WAVECAP) { tkey[j] = k; tsd[j] = sd; }
        }
      }
    }
    __syncthreads();
    int n2 = lcnt;
    if (n2 == 0) break;
    bool totail = (n2 <= WAVECAP);
    // Phase B: locally-dominant edges match (prefetched on global path)
    u32 sd_q = 0; u64 k_q = 0;
    if (!totail && tid < n2) { sd_q = sout[tid]; k_q = kout[tid]; }
    for (int i = tid; i < n2; i += 1024) {
      u32 sd; u64 k;
      if (totail) { sd = tsd[i]; k = tkey[i]; }
      else {
        sd = sd_q; k = k_q;
        int inx = i + 1024;
        if (inx < n2) { sd_q = sout[inx]; k_q = kout[inx]; }
      }
      int s = sd >> 16, d = sd & 0xffff;
      u64 val = etag | k;
      if (bcur[s] == val && (d == s || bcur[d] == val)) {
        matched[(u32)(k & 0xFFFFF)] = ~((u32)(k >> 20));
        dead_s[s] = 1;
        dead_s[d] = 1;
      }
    }
    if (tid == 0) lcnt = 0;
    __syncthreads();
    if (totail) {
      // ---- R14: LDS-resident full-block rounds (list <= WAVECAP) ----
      int nt = n2;
      int rr = round + 1;
      int cur = 0;
      while (nt > 64 && rr < 4000) {
        u64 et2 = (u64)(4095 - rr) << 52;
        u64* ks = cur ? tkey2 : tkey;
        u32* ss = cur ? tsd2 : tsd;
        u64* kd_ = cur ? tkey : tkey2;
        u32* sd_ = cur ? tsd : tsd2;
        int* cdst = cur ? &lcnt : &lcnt2;
        if (tid == 0) *cdst = 0;
        // claim pass
        for (int i = tid; i < nt; i += 1024) {
          u32 sd = ss[i];
          int s = sd >> 16, d = sd & 0xffff;
          if (dead_s[s] | dead_s[d]) continue;
          u64 val = et2 | ks[i];
          atomicMin(&bcur[s], val);
          if (d != s) atomicMin(&bcur[d], val);
        }
        __syncthreads();  // claims + cdst reset visible
        // fused test + compact into other buffer (order nondeterministic,
        // matching is key-determined -> result exact; dead_s races only
        // add stale entries, filtered by later alive-checks)
        for (int i = tid; i - lane < nt; i += 1024) {
          bool inb = i < nt;
          u32 sd = 0; u64 k = 0;
          if (inb) { sd = ss[i]; k = ks[i]; }
          int s = sd >> 16, d = sd & 0xffff;
          bool alive = false;
          if (inb && !(dead_s[s] | dead_s[d])) {
            u64 val = et2 | k;
            if (bcur[s] == val && (d == s || bcur[d] == val)) {
              matched[(u32)(k & 0xFFFFF)] = ~((u32)(k >> 20));
              dead_s[s] = 1;
              dead_s[d] = 1;
            } else {
              alive = true;
            }
          }
          u64 m = __ballot(alive);
          if (m) {
            int lead = __ffsll((long long)m) - 1;
            int bse = 0;
            if (lane == lead) bse = atomicAdd(cdst, __popcll(m));
            bse = __shfl(bse, lead, 64);
            if (alive) {
              int j = bse + __popcll(m & ((1ull << lane) - 1ull));
              kd_[j] = k;
              sd_[j] = sd;
            }
          }
        }
        __syncthreads();  // deaths + appends complete
        nt = cur ? lcnt : lcnt2;
        cur ^= 1;
        ++rr;
      }
      if (nt > 0) {
        if (tid < 64) {
          // ---- one-shot exact greedy over <=64 edges (single wave) ----
          // list may contain stale-dead entries -> re-check dead_s (list
          // and dead_s are stable here: barrier above).
          u64* ks = cur ? tkey2 : tkey;
          u32* ss = cur ? tsd2 : tsd;
          u64 myk = 0; u32 mysd = 0;
          bool have = lane < nt;
          if (have) { myk = ks[lane]; mysd = ss[lane]; }
          int ms = mysd >> 16, md = mysd & 0xffff;
          if (have && (dead_s[ms] | dead_s[md])) have = false;
          u64 C = 0;
          for (int j = 0; j < nt; ++j) {
            int js = __shfl(ms, j, 64);
            int jd = __shfl(md, j, 64);
            u64 jk = __shfl(myk, j, 64);
            int jh = __shfl((int)have, j, 64);
            bool conf = have && jh && j != lane && jk < myk &&
                        (js == ms || js == md || jd == ms || jd == md);
            if (conf) C |= 1ull << j;
          }
          u64 undec = __ballot(have);
          u64 M = 0;
          while (undec) {
            bool rdy = have && ((undec >> lane) & 1ull) && (C & undec) == 0;
            bool mt = rdy && (C & M) == 0;
            u64 rdym = __ballot(rdy);
            u64 mm = __ballot(mt);
            M |= mm;
            undec &= ~rdym;
            if (!rdym) break;  // safety: DAG guarantees progress
          }
          if (have && ((M >> lane) & 1ull)) {
            matched[(u32)(myk & 0xFFFFF)] = ~((u32)(myk >> 20));
            dead_s[ms] = 1;
            dead_s[md] = 1;
          }
        }
        __syncthreads();
      }
      break;
    }
    u64* tk = kin; kin = kout; kout = tk;
    u32* ts = sin_; sin_ = sout; sout = ts;
    n = n2;
  }
  __syncthreads();
  for (int i = tid; i < per; i += 1024) dead[base + i] = dead_s[i];
}

#define HBITS 21
#define HMASK ((1u << HBITS) - 1u)

// R7 two-phase cluster build (512 blocks); also zeroes cnt.
// R16: matched carries score bits -> per-cluster gsc.
// R23: also ~0-inits the dedup hash table (decouples newx from dedup).
__global__ void k_build2(const u32* __restrict__ matched, const int* __restrict__ src,
                         const int* __restrict__ dst, const int* __restrict__ batch,
                         const u8* __restrict__ dead, int* __restrict__ cluster,
                         int* __restrict__ new_batch, int* __restrict__ srcE,
                         float* __restrict__ gsc, u64* __restrict__ table,
                         int* __restrict__ nclus, float* __restrict__ gccnt,
                         int* __restrict__ cnt, int e, int n, int nc) {
  __shared__ int c_cnt, c_off, basep;
  __shared__ int sc[8];
  if (threadIdx.x == 0) { c_cnt = 0; c_off = 0; basep = 0; }
  if (threadIdx.x < 8) sc[threadIdx.x] = 0;
  __syncthreads();
  int nbk = gridDim.x;
  for (int i = blockIdx.x * blockDim.x + threadIdx.x; i < nc; i += nbk * blockDim.x) cnt[i] = 0;
  for (int i = blockIdx.x * blockDim.x + threadIdx.x; i < (1 << HBITS); i += nbk * blockDim.x)
    table[i] = ~0ull;
  int ec = (e + nbk - 1) / nbk, es = blockIdx.x * ec, ee = es + ec; if (ee > e) ee = e;
  int nk = (n + nbk - 1) / nbk, ns = blockIdx.x * nk, ne = ns + nk; if (ne > n) ne = n;
  int my = 0;
  for (int i = es + threadIdx.x; i < ee; i += blockDim.x) if (matched[i]) ++my;
  for (int i = ns + threadIdx.x; i < ne; i += blockDim.x) if (!dead[i]) ++my;
  if (my) atomicAdd(&c_cnt, my);
  __syncthreads();
  if (threadIdx.x == 0 && c_cnt) basep = atomicAdd(nclus, c_cnt);
  __syncthreads();
  int bse = basep;
  for (int i = es + threadIdx.x; i < ee; i += blockDim.x) {
    u32 m = matched[i];
    if (!m) continue;
    int c = bse + atomicAdd(&c_off, 1);
    int s = src[i], d = dst[i];
    cluster[s] = c;
    cluster[d] = c;
    srcE[c] = i;
    gsc[c] = __uint_as_float(m);
    int g = batch[s];
    new_batch[c] = g;
    if ((unsigned)g < 8u) atomicAdd(&sc[g], 1);
  }
  for (int i = ns + threadIdx.x; i < ne; i += blockDim.x) {
    if (dead[i]) continue;
    int c = bse + atomicAdd(&c_off, 1);
    cluster[i] = c;
    srcE[c] = ~i;  // singleton: encoded node
    gsc[c] = 1.0f;
    int g = batch[i];
    new_batch[c] = g;
    if ((unsigned)g < 8u) atomicAdd(&sc[g], 1);
  }
  __syncthreads();
  if (threadIdx.x < 8 && sc[threadIdx.x] > 0)
    atomicAdd(&gccnt[threadIdx.x], (float)sc[threadIdx.x]);
}

// R23: fused new_x (wave per cluster) + edge dedup (thread per edge).
// Both consume only build2 outputs (table pre-initialized there) and write
// disjoint outputs -> one dispatch, concurrent memory-bound phases.
__global__ void k_nd(const int* __restrict__ srcE, const int* __restrict__ src,
                     const int* __restrict__ dst, const float* __restrict__ gsc,
                     const int* __restrict__ nclusP, const float* __restrict__ h2,
                     float* __restrict__ new_x, u64* __restrict__ table,
                     const int* __restrict__ cluster, int* __restrict__ ns,
                     int* __restrict__ nd, int* __restrict__ cnt, int e, int n) {
  int idx = blockIdx.x * blockDim.x + threadIdx.x;
  // ---- dedup role (thread per edge) ----
  if (idx < e) {
    int cs_ = cluster[src[idx]], cd_ = cluster[dst[idx]];
    u64 kk = (u64)cs_ * (u64)(n + 1) + (u64)cd_;
    u32 pos = (u32)((kk * 0x9E3779B97F4A7C15ull) >> 43) & HMASK;
    while (true) {
      u64 old = atomicCAS(&table[pos], ~0ull, kk);
      if (old == ~0ull) {
        ns[idx] = cs_; nd[idx] = cd_;
        atomicAdd(&cnt[cd_], 1);
        break;
      }
      if (old == kk) { ns[idx] = n; nd[idx] = n; break; }
      pos = (pos + 1) & HMASK;
    }
  }
  // ---- new_x role (wave per cluster) ----
  int c = idx >> 6;
  int lane = idx & 63;
  if (c >= n || c >= *nclusP) return;
  int v = srcE[c];
  float val;
  if (v >= 0) {
    int s = src[v], d = dst[v];
    val = h2[(size_t)s * 64 + lane];
    if (d != s) val += h2[(size_t)d * 64 + lane];
    val *= gsc[c];
  } else {
    val = h2[(size_t)(~v) * 64 + lane];
  }
  new_x[(size_t)c * 64 + lane] = val;
}

// JK cat (partial-buffer reduce) + lin1 + relu + lin2 + log_softmax.
// R16: one block per graph (was 1 block total).  FP order identical.
__global__ void k_head(const float* __restrict__ xs_part /*[4][64][512]*/,
                       const float* __restrict__ gn_part /*[64][8]*/,
                       const float* __restrict__ gccnt,
                       const float* __restrict__ l1w, const float* __restrict__ l1b,
                       const float* __restrict__ l2w, const float* __restrict__ l2b,
                       const int* __restrict__ gP, float* __restrict__ out, int C) {
  __shared__ float z[256];
  __shared__ float z1[64];
  __shared__ float z2[16];
  __shared__ float gnc;
  int G = *gP;
  int g = blockIdx.x;
  if (g >= G) return;
  int tid = threadIdx.x;
  if (tid < 64) {
    float s = gn_part[tid * 8 + g];
#pragma unroll
    for (int off = 32; off > 0; off >>= 1) s += __shfl_down(s, off, 64);
    if (tid == 0) gnc = s;
  }
  __syncthreads();
  {
    int p = tid >> 6, f = tid & 63;
    const float* xp = xs_part + (size_t)p * 64 * 512;
    float s = 0.f;
    for (int b = 0; b < 64; ++b) s += xp[b * 512 + g * 64 + f];
    float c = (p < 2) ? gnc : gccnt[g];
    if (c < 1.f) c = 1.f;
    z[tid] = s / c;
  }
  __syncthreads();
  if (tid < 64) {
    int o = tid;
    float a = l1b[o];
    for (int k = 0; k < 256; ++k) a = fmaf(z[k], l1w[o * 256 + k], a);
    z1[o] = a > 0.f ? a : 0.f;
  }
  __syncthreads();
  if (tid < C) {
    int c = tid;
    float a = l2b[c];
    for (int k = 0; k < 64; ++k) a = fmaf(z1[k], l2w[c * 64 + k], a);
    z2[c] = a;
  }
  __syncthreads();
  if (tid == 0) {
    float m = z2[0];
    for (int c = 1; c < C; ++c) m = fmaxf(m, z2[c]);
    float s = 0.f;
    for (int c = 0; c < C; ++c) s += expf(z2[c] - m);
    float lse = m + logf(s);
    for (int c = 0; c < C; ++c) out[g * C + c] = z2[c] - lse;
  }
}

extern "C" void kernel_launch(void* const* d_in, const int* in_sizes, int n_in,
                              void* d_out, int out_size, void* d_ws, size_t ws_size,
                              hipStream_t stream) {
  const float* x       = (const float*)d_in[0];
  const int*   ei      = (const int*)d_in[1];
  const int*   batch   = (const int*)d_in[2];
  const float* w_rel1  = (const float*)d_in[3];
  const float* b_rel1  = (const float*)d_in[4];
  const float* w_root1 = (const float*)d_in[5];
  const float* w_rel2  = (const float*)d_in[6];
  const float* b_rel2  = (const float*)d_in[7];
  const float* w_root2 = (const float*)d_in[8];
  const float* w_rel3  = (const float*)d_in[9];
  const float* b_rel3  = (const float*)d_in[10];
  const float* w_root3 = (const float*)d_in[11];
  const float* w_rel4  = (const float*)d_in[12];
  const float* b_rel4  = (const float*)d_in[13];
  const float* w_root4 = (const float*)d_in[14];
  const float* pool_w  = (const float*)d_in[15];
  const float* pool_b  = (const float*)d_in[16];
  const float* lin1_w  = (const float*)d_in[17];
  const float* lin1_b  = (const float*)d_in[18];
  const float* lin2_w  = (const float*)d_in[19];
  const float* lin2_b  = (const float*)d_in[20];
  const int*   gP      = (const int*)d_in[21];
  float* out = (float*)d_out;

  const int N = in_sizes[2];
  const int E = in_sizes[1] / 2;
  const int C = in_sizes[20];
  const int* src = ei;
  const int* dst = ei + E;

  // ---- workspace layout ----
  char* w = (char*)d_ws;
  auto alloc = [&](size_t bytes) -> char* {
    char* p = w;
    w += (bytes + 255) & ~(size_t)255;
    return p;
  };
  float* r      = (float*)alloc((size_t)N * 64 * 4);
  float* agg    = (float*)alloc((size_t)(N + 1) * 64 * 4);  // u / match lists / hash
  float* hA     = (float*)alloc((size_t)N * 64 * 4);        // h1 -> new_x -> h4
  float* hB     = (float*)alloc((size_t)N * 64 * 4);        // h2 -> h3
  float* gsc    = (float*)alloc((size_t)(N + 2) * 4);       // per-cluster score
  int*   colbuf = (int*)alloc((size_t)E * 8);               // col + eid
  int*   listA  = (int*)alloc((size_t)E * 4);               // aN -> ns
  int*   listB  = (int*)alloc((size_t)E * 4);               // bN -> nd
  int*   rowptr = (int*)alloc((size_t)(N + 2) * 4);
  int*   pos    = (int*)alloc((size_t)(N + 2) * 4);         // also srcE
  char* zstart = w;                                         // zeroed block
  int*   cnt       = (int*)alloc((size_t)(N + 2) * 4);
  int*   bsum      = (int*)alloc(1024);
  u8*    dead      = (u8*)alloc((size_t)N);
  u32*   matched   = (u32*)alloc((size_t)E * 4);            // score bits or 0
  int*   cluster   = (int*)alloc((size_t)N * 4);
  int*   new_batch = (int*)alloc((size_t)N * 4);
  float* xs_part   = (float*)alloc((size_t)4 * 64 * 512 * 4);  // per-stage partials
  float* gn_part   = (float*)alloc((size_t)64 * 8 * 4);
  float* small     = (float*)alloc(16384);
  size_t zbytes = (size_t)(w - zstart);
  if ((size_t)(w - (char*)d_ws) > ws_size) return;  // fail loudly

  int*   col = colbuf;         // CSR src per slot
  int*   eid = colbuf + E;     // CSR original-edge id per slot
  float* aN  = (float*)listA;  // alias: dots dead before ns/nd used
  float* bN  = (float*)listB;
  float* uB  = agg;            // u for all convs (agg phase-disjoint)
  u64*   keyA = (u64*)agg;     // score/key output + match ping-pong
  u64*   keyB = keyA + E;
  u32*   sdA  = (u32*)(keyB + E);
  u32*   sdB  = sdA + E;
  u64*   bcur0 = (u64*)(sdB + E);  // round-0 global minima (tail of agg)
  u64*   table = (u64*)agg;    // hash (after match, before conv3)
  int*   srcE = pos;           // alias: pos re-filled later by 2nd scan_out

  float* gccnt  = small;                 // [8]
  int*   nclusP = (int*)(small + 16);
  int*   gposM  = (int*)(small + 32);    // [8] alive-list counters (zeroed)

  const int TB = 256;
  const int chunks = (((N + 511) / 512) + 7) & ~7;  // %8==0 for XCD grouping
  const int gT = chunks * 4;                        // x: {xcd, oq, chunk}
  const int gN = (N + TB - 1) / TB;
  const int gE = (E + TB - 1) / TB;
  const int gE1k = (E + 1023) >> 10;
  const int gNw = (int)(((size_t)N * 64 + TB - 1) / TB);  // wave per node
  const int swz = (gNw % 8 == 0) ? 1 : 0;
  const int nc = N + 2;
  const int nb = (nc + 1023) / 1024;

  hipMemsetAsync(zstart, 0, zbytes, stream);

  // ---- CSR for original edges ----
  k_count<<<gE1k, TB, 0, stream>>>(dst, cnt, E);
  k_scan_sums<<<nb, TB, 0, stream>>>(cnt, bsum, nc);
  k_scan_out<<<nb, TB, 0, stream>>>(cnt, bsum, rowptr, pos, nc, nb);
  k_fill<<<gE, TB, 0, stream>>>(src, dst, pos, col, eid, bcur0, N, E, N);

  // ---- conv1 (F=128 -> 64) ----
  k_transform2<128><<<gT, TB, 0, stream>>>(x, w_rel1, w_root1, b_rel1, nullptr, r, uB, N);
  k_gfin2<<<gNw, TB, 0, stream>>>(r, uB, rowptr, col, batch, gP, nullptr, hA,
                                  nullptr, nullptr, nullptr, xs_part + 0 * 32768, gn_part, N, swz);

  // ---- conv2 (64 -> 64, + score dots) ----
  k_transform2<64><<<gT, TB, 0, stream>>>(hA, w_rel2, w_root2, b_rel2, nullptr, r, uB, N);
  k_gfin2<<<gNw, TB, 0, stream>>>(r, uB, rowptr, col, batch, gP, nullptr, hB,
                                  pool_w, aN, bN, xs_part + 1 * 32768, nullptr, N, swz);

  // ---- scoring (CSR order) + grid-wide matching round 0 ----
  k_score_csr<<<gN, TB, 0, stream>>>(aN, bN, pool_b, rowptr, col, eid, gP,
                                     keyA, sdA, bcur0, N);
  k_match0<<<gN, TB, 0, stream>>>(src, dst, bcur0, matched, dead, N);
  k_list0<<<gN, TB, 0, stream>>>(rowptr, gP, keyA, sdA, dead, keyB, sdB, gposM, N);

  // ---- greedy matching rounds 1+ (per-graph WG, LDS state, LDS tail) ----
  k_match_wg<<<8, 1024, 0, stream>>>(rowptr, gP, gposM, keyB, keyA, sdB, sdA,
                                     dead, matched, N);

  // ---- clusters (+table init), fused new_x/dedup, pooled CSR ----
  k_build2<<<512, TB, 0, stream>>>(matched, src, dst, batch, dead, cluster, new_batch,
                                   srcE, gsc, table, nclusP, gccnt, cnt, E, N, nc);
  k_nd<<<gNw, TB, 0, stream>>>(srcE, src, dst, gsc, nclusP, hB, hA, table,
                               cluster, listA, listB, cnt, E, N);
  k_scan_sums<<<nb, TB, 0, stream>>>(cnt, bsum, nc);
  k_scan_out<<<nb, TB, 0, stream>>>(cnt, bsum, rowptr, pos, nc, nb);
  k_fill<<<gE, TB, 0, stream>>>(listA, listB, pos, col, nullptr, nullptr, 0, E, N);

  // ---- conv3 (64 -> 64, pooled) ----
  k_transform2<64><<<gT, TB, 0, stream>>>(hA, w_rel3, w_root3, b_rel3, nclusP, r, uB, N);
  k_gfin2<<<gNw, TB, 0, stream>>>(r, uB, rowptr, col, new_batch, gP, nclusP, hB,
                                  nullptr, nullptr, nullptr, xs_part + 2 * 32768, nullptr, N, 0);

  // ---- conv4 (64 -> 64, pooled) ----
  k_transform2<64><<<gT, TB, 0, stream>>>(hB, w_rel4, w_root4, b_rel4, nclusP, r, uB, N);
  k_gfin2<<<gNw, TB, 0, stream>>>(r, uB, rowptr, col, new_batch, gP, nclusP, hA,
                                  nullptr, nullptr, nullptr, xs_part + 3 * 32768, nullptr, N, 0);

  // ---- head ----
  k_head<<<8, TB, 0, stream>>>(xs_part, gn_part, gccnt, lin1_w, lin1_b, lin2_w, lin2_b, gP, out, C);
}